// Round 2
// baseline (2816.984 us; speedup 1.0000x reference)
//
#include <hip/hip_runtime.h>
#include <math.h>

// Shapes
#define NN   9216          // 96*96
#define CCH  128
#define LL   256

// Workspace layout (float offsets)
#define OFF_X1   0                 // 16*128*9216 = 18874368
#define OFF_CS   18874368          // 16*9216    = 147456
#define OFF_SPRE 19021824          // 4096  (zeroed)
#define OFF_STAQ 19025920          // 4096  (zeroed)
#define OFF_BSUM 19030016          // 16    (zeroed)
#define OFF_BM2  19030032          // 16    (zeroed)
#define OFF_BM4  19030048          // 16    (zeroed)
#define OFF_BMAX 19030064          // 16 uint (zeroed; cs>0 so 0 is safe identity)
#define OFF_BMIN 19030080          // 16 uint (0xFFFFFFFF)
#define OFF_PAR  19030096          // 64: per-b {absK, cmin, range, thresh}
#define OFF_WV   19030160          // 2*128 folded V weights
#define OFF_BV   19030416          // 2
#define OFF_PBS  19030418          // 1

// ---------------------------------------------------------------- k0: fold proj/V path
__global__ void k0_prep(const float* __restrict__ qkv_w, const float* __restrict__ qkv_b,
                        const float* __restrict__ proj_w, const float* __restrict__ proj_b,
                        float* __restrict__ wsf) {
    __shared__ float psum[128];
    int t = threadIdx.x;
    if (t < 128) {
        float s = 0.f;
        for (int c = 0; c < 128; ++c) s += proj_w[c * 128 + t];
        psum[t] = s;
    }
    __syncthreads();
    {   // wv[h][c] = sum_j qkv_w[256+h*64+j][c] * psum[h*64+j]
        int h = t >> 7, c = t & 127;
        float s = 0.f;
        for (int j = 0; j < 64; ++j)
            s += qkv_w[(size_t)(256 + h * 64 + j) * 128 + c] * psum[h * 64 + j];
        wsf[OFF_WV + h * 128 + c] = s;
    }
    if (t < 2) {
        float s = 0.f;
        for (int j = 0; j < 64; ++j) s += qkv_b[256 + t * 64 + j] * psum[t * 64 + j];
        wsf[OFF_BV + t] = s;
    }
    if (t == 0) {
        float s = 0.f;
        for (int c = 0; c < 128; ++c) s += proj_b[c];
        wsf[OFF_PBS] = s;
    }
}

// ---------------------------------------------------------------- k1: conv3x3 + BN + LeakyReLU
// Block: 256 threads = 32 rows x 8 cols-of-4. Tile 32x32 spatial, 16 oc. Grid (9, 8 og, 16 b).
__global__ __launch_bounds__(256) void k1_conv(
    const float* __restrict__ x, const float* __restrict__ w,
    const float* __restrict__ g, const float* __restrict__ bb,
    const float* __restrict__ m, const float* __restrict__ v,
    float* __restrict__ x1) {
    __shared__ __align__(16) float tin[34 * 36];
    __shared__ __align__(16) float wl[9 * 16];
    int tid = threadIdx.x;
    int bx = blockIdx.x, og = blockIdx.y, b = blockIdx.z;
    int x0 = (bx % 3) * 32, y0 = (bx / 3) * 32;
    int ty = tid >> 3, tx = tid & 7;

    float acc[16][4];
#pragma unroll
    for (int o = 0; o < 16; ++o)
#pragma unroll
        for (int p = 0; p < 4; ++p) acc[o][p] = 0.f;

    const float* xb = x + (size_t)b * 256 * NN;
    const float* wb = w + (size_t)(og * 16) * 2304;

    for (int ic = 0; ic < 256; ++ic) {
        __syncthreads();
        for (int idx = tid; idx < 34 * 34; idx += 256) {
            int r = idx / 34, c = idx % 34;
            int gy = y0 - 1 + r, gx = x0 - 1 + c;
            float vv = 0.f;
            if (gy >= 0 && gy < 96 && gx >= 0 && gx < 96) vv = xb[(size_t)ic * NN + gy * 96 + gx];
            tin[r * 36 + c] = vv;
        }
        if (tid < 144) {
            int k = tid / 16, oc = tid % 16;
            wl[k * 16 + oc] = wb[(size_t)oc * 2304 + ic * 9 + k];
        }
        __syncthreads();

        float ti[3][8];
#pragma unroll
        for (int r = 0; r < 3; ++r) {
            float4 a  = *(const float4*)&tin[(ty + r) * 36 + tx * 4];
            float4 b4 = *(const float4*)&tin[(ty + r) * 36 + tx * 4 + 4];
            ti[r][0] = a.x;  ti[r][1] = a.y;  ti[r][2] = a.z;  ti[r][3] = a.w;
            ti[r][4] = b4.x; ti[r][5] = b4.y; ti[r][6] = b4.z; ti[r][7] = b4.w;
        }
#pragma unroll
        for (int kh = 0; kh < 3; ++kh)
#pragma unroll
            for (int kw = 0; kw < 3; ++kw) {
                float wr[16];
#pragma unroll
                for (int q = 0; q < 4; ++q) {
                    float4 wq = *(const float4*)&wl[(kh * 3 + kw) * 16 + q * 4];
                    wr[q * 4 + 0] = wq.x; wr[q * 4 + 1] = wq.y;
                    wr[q * 4 + 2] = wq.z; wr[q * 4 + 3] = wq.w;
                }
#pragma unroll
                for (int p = 0; p < 4; ++p) {
                    float iv = ti[kh][kw + p];
#pragma unroll
                    for (int o = 0; o < 16; ++o) acc[o][p] += iv * wr[o];
                }
            }
    }
#pragma unroll
    for (int o = 0; o < 16; ++o) {
        int oc = og * 16 + o;
        float sc = g[oc] / sqrtf(v[oc] + 1e-5f);
        float bo = bb[oc] - m[oc] * sc;
        float4 outv;
        float t0;
        t0 = acc[o][0] * sc + bo; outv.x = t0 > 0.f ? t0 : 0.01f * t0;
        t0 = acc[o][1] * sc + bo; outv.y = t0 > 0.f ? t0 : 0.01f * t0;
        t0 = acc[o][2] * sc + bo; outv.z = t0 > 0.f ? t0 : 0.01f * t0;
        t0 = acc[o][3] * sc + bo; outv.w = t0 > 0.f ? t0 : 0.01f * t0;
        *(float4*)&x1[((size_t)b * 128 + oc) * NN + (y0 + ty) * 96 + x0 + tx * 4] = outv;
    }
}

// ---------------------------------------------------------------- k3: windowed attention -> pooled s
// One block per window (196 per b). LN + QK gemm + bias + softmax + collapsed V/proj path.
__global__ __launch_bounds__(256) void k3_attn(
    const float* __restrict__ x1, const float* __restrict__ ln_g, const float* __restrict__ ln_b,
    const float* __restrict__ qkv_w, const float* __restrict__ qkv_b,
    const float* __restrict__ rpe, const float* __restrict__ wsf,
    float* __restrict__ spre) {
    __shared__ __align__(16) float T[49 * 132];   // tokens; reused as S[2][49][52]
    __shared__ __align__(16) float Qs[49 * 132];
    __shared__ __align__(16) float Ks[49 * 132];
    __shared__ float vps[49 * 2];
    __shared__ float mstat[49], rstat[49];
    int tid = threadIdx.x;
    int wwin = blockIdx.x, b = blockIdx.y;
    int wh = wwin / 14, ww = wwin % 14;

    // stage tokens (zero outside image)
    for (int idx = tid; idx < 128 * 49; idx += 256) {
        int c = idx / 49, i = idx % 49;
        int th = wh * 7 + i / 7, tw = ww * 7 + i % 7;
        float vv = 0.f;
        if (th < 96 && tw < 96) vv = x1[((size_t)b * 128 + c) * NN + th * 96 + tw];
        T[i * 132 + c] = vv;
    }
    __syncthreads();
    // LN stats (two-pass, matches reference)
    if (tid < 49) {
        float s = 0.f;
        for (int c4 = 0; c4 < 128; c4 += 4) {
            float4 t4 = *(const float4*)&T[tid * 132 + c4];
            s += t4.x + t4.y + t4.z + t4.w;
        }
        float mean = s * (1.f / 128.f);
        float vs = 0.f;
        for (int c4 = 0; c4 < 128; c4 += 4) {
            float4 t4 = *(const float4*)&T[tid * 132 + c4];
            float d0 = t4.x - mean, d1 = t4.y - mean, d2 = t4.z - mean, d3 = t4.w - mean;
            vs += d0 * d0 + d1 * d1 + d2 * d2 + d3 * d3;
        }
        mstat[tid] = mean;
        rstat[tid] = 1.f / sqrtf(vs * (1.f / 128.f) + 1e-6f);
    }
    __syncthreads();
    // normalize in place; padded tokens forced to 0 (reference pads AFTER LN)
    for (int idx = tid; idx < 49 * 128; idx += 256) {
        int i = idx >> 7, c = idx & 127;
        int th = wh * 7 + i / 7, tw = ww * 7 + i % 7;
        float vv = T[i * 132 + c];
        float nv = (vv - mstat[i]) * rstat[i] * ln_g[c] + ln_b[c];
        T[i * 132 + c] = (th < 96 && tw < 96) ? nv : 0.f;
    }
    __syncthreads();
    // Q,K gemm: thread -> 2 out-channels (o2,o2+1), 25 rows (row 24 duplicated across halves)
    {
        int o2 = (tid & 127) * 2;
        int i0 = (tid >> 7) * 24;
        float a0[25], a1[25];
#pragma unroll
        for (int ii = 0; ii < 25; ++ii) { a0[ii] = 0.f; a1[ii] = 0.f; }
        for (int cc = 0; cc < 128; cc += 4) {
            float4 wa = *(const float4*)&qkv_w[(size_t)o2 * 128 + cc];
            float4 wc = *(const float4*)&qkv_w[(size_t)(o2 + 1) * 128 + cc];
#pragma unroll
            for (int ii = 0; ii < 25; ++ii) {
                float4 t4 = *(const float4*)&T[(i0 + ii) * 132 + cc];
                a0[ii] += t4.x * wa.x + t4.y * wa.y + t4.z * wa.z + t4.w * wa.w;
                a1[ii] += t4.x * wc.x + t4.y * wc.y + t4.z * wc.z + t4.w * wc.w;
            }
        }
        float bq0 = qkv_b[o2], bq1 = qkv_b[o2 + 1];
        float* dst = (o2 < 128) ? Qs : Ks;
        int oo = o2 & 127;
#pragma unroll
        for (int ii = 0; ii < 25; ++ii) {
            dst[(i0 + ii) * 132 + oo]     = a0[ii] + bq0;
            dst[(i0 + ii) * 132 + oo + 1] = a1[ii] + bq1;
        }
    }
    // vps[i][h] = sum_c T[i][c]*wv[h][c] + bv[h]
    if (tid < 98) {
        int i = tid >> 1, h = tid & 1;
        float s = wsf[OFF_BV + h];
        for (int c = 0; c < 128; ++c) s += T[i * 132 + c] * wsf[OFF_WV + h * 128 + c];
        vps[i * 2 + h] = s;
    }
    __syncthreads();
    // logits: S[h][i][j] = q.k/8 + rpe bias  (S overlays T)
    {
        int h = tid >> 7, i = tid & 127;
        if (i < 49) {
            float qr[64];
#pragma unroll
            for (int d4 = 0; d4 < 64; d4 += 4) {
                float4 q4 = *(const float4*)&Qs[i * 132 + h * 64 + d4];
                qr[d4] = q4.x; qr[d4 + 1] = q4.y; qr[d4 + 2] = q4.z; qr[d4 + 3] = q4.w;
            }
            int ih7 = i / 7, iw7 = i % 7;
            for (int j = 0; j < 49; ++j) {
                float s = 0.f;
#pragma unroll
                for (int d4 = 0; d4 < 64; d4 += 4) {
                    float4 k4 = *(const float4*)&Ks[j * 132 + h * 64 + d4];
                    s += qr[d4] * k4.x + qr[d4 + 1] * k4.y + qr[d4 + 2] * k4.z + qr[d4 + 3] * k4.w;
                }
                int relidx = (ih7 - j / 7 + 6) * 13 + (iw7 - j % 7 + 6);
                T[(h * 49 + i) * 52 + j] = s * 0.125f + rpe[relidx * 2 + h];
            }
        }
    }
    __syncthreads();
    // softmax per row
    {
        int h = tid >> 7, i = tid & 127;
        if (i < 49) {
            float r[49];
            float* row = &T[(h * 49 + i) * 52];
#pragma unroll
            for (int j = 0; j < 49; ++j) r[j] = row[j];
            float mx = r[0];
#pragma unroll
            for (int j = 1; j < 49; ++j) mx = fmaxf(mx, r[j]);
            float sum = 0.f;
#pragma unroll
            for (int j = 0; j < 49; ++j) { r[j] = expf(r[j] - mx); sum += r[j]; }
            float inv = 1.f / sum;
#pragma unroll
            for (int j = 0; j < 49; ++j) row[j] = r[j] * inv;
        }
    }
    __syncthreads();
    // per-token channel-sum of attention output via collapsed V/proj; pool into spre
    if (tid < 49) {
        int i = tid;
        int th = wh * 7 + i / 7, tw = ww * 7 + i % 7;
        float s = wsf[OFF_PBS];
        for (int h = 0; h < 2; ++h)
            for (int j = 0; j < 49; ++j)
                s += T[(h * 49 + i) * 52 + j] * vps[j * 2 + h];
        if (th < 96 && tw < 96) {
            int l = (th * 96 + tw) / 36;
            atomicAdd(&spre[b * 256 + l], s);
        }
    }
}

// ---------------------------------------------------------------- k4: cs = sigmoid(conv2.x1), + sum/min/max
__global__ __launch_bounds__(256) void k4_cs(
    const float* __restrict__ x1, const float* __restrict__ w2,
    float* __restrict__ csb, float* __restrict__ bsum,
    unsigned* __restrict__ bmin, unsigned* __restrict__ bmax) {
    int b = blockIdx.y;
    int n = blockIdx.x * 256 + threadIdx.x;
    float s = 0.f;
    for (int c = 0; c < 128; ++c) s += w2[c] * x1[((size_t)b * 128 + c) * NN + n];
    float csv = 1.f / (1.f + expf(-s));
    csb[(size_t)b * NN + n] = csv;
    float ss = csv, mn = csv, mx = csv;
    for (int o = 32; o > 0; o >>= 1) {
        ss += __shfl_down(ss, o, 64);
        mn = fminf(mn, __shfl_down(mn, o, 64));
        mx = fmaxf(mx, __shfl_down(mx, o, 64));
    }
    if ((threadIdx.x & 63) == 0) {
        atomicAdd(&bsum[b], ss);
        atomicMin(&bmin[b], __float_as_uint(mn));
        atomicMax(&bmax[b], __float_as_uint(mx));
    }
}

// ---------------------------------------------------------------- k5: central moments
__global__ __launch_bounds__(256) void k5_mom(
    const float* __restrict__ csb, const float* __restrict__ bsum,
    float* __restrict__ bm2, float* __restrict__ bm4) {
    int b = blockIdx.y;
    int n = blockIdx.x * 256 + threadIdx.x;
    float mu = bsum[b] * (1.f / 9216.f);
    float d = csb[(size_t)b * NN + n] - mu;
    float d2 = d * d, d4 = d2 * d2;
    for (int o = 32; o > 0; o >>= 1) {
        d2 += __shfl_down(d2, o, 64);
        d4 += __shfl_down(d4, o, 64);
    }
    if ((threadIdx.x & 63) == 0) { atomicAdd(&bm2[b], d2); atomicAdd(&bm4[b], d4); }
}

// ---------------------------------------------------------------- k5b: per-b params
__global__ void k5b_par(const float* __restrict__ bsum, const float* __restrict__ bm2,
                        const float* __restrict__ bm4, const unsigned* __restrict__ bmin,
                        const unsigned* __restrict__ bmax, float* __restrict__ par) {
    int b = threadIdx.x;
    if (b >= 16) return;
    float n = 9216.f;
    float m2 = bm2[b], m4 = bm4[b];
    float var = m2 / (n - 1.f);
    float t1 = n * (n + 1.f) / ((n - 1.f) * (n - 2.f) * (n - 3.f)) * m4 / (var * var);
    float t2 = 3.f * ((n - 1.f) * (n - 1.f)) / ((n - 2.f) * (n - 3.f));
    float kurt = t1 - t2;
    float cmin = __uint_as_float(bmin[b]);
    float cmax = __uint_as_float(bmax[b]);
    float range = cmax - cmin;
    float ql0 = (1.f / 512.f) * range + cmin;   // reference op order
    float ql1 = (3.f / 512.f) * range + cmin;
    float inter = ql1 - ql0;
    par[b * 4 + 0] = fabsf(kurt);
    par[b * 4 + 1] = cmin;
    par[b * 4 + 2] = range;
    par[b * 4 + 3] = 1.f - inter;
}

// ---------------------------------------------------------------- k6: quant output + sta sums
__global__ __launch_bounds__(256) void k6_quant(
    const float* __restrict__ csb, const float* __restrict__ par,
    float* __restrict__ outq, float* __restrict__ staq) {
    int b = blockIdx.y;
    int n0 = blockIdx.x * 64;
    int l = threadIdx.x;
    float absK = par[b * 4 + 0], cmin = par[b * 4 + 1];
    float range = par[b * 4 + 2], thr = par[b * 4 + 3];
    float qlv = ((float)(2 * l + 1) * (1.f / 512.f)) * range + cmin;
    float lsum = 0.f;
    for (int j = 0; j < 64; ++j) {
        float csv = csb[(size_t)b * NN + n0 + j];
        float d = fabsf(qlv - csv);
        float q0 = 1.f - d;
        float qv = absK * expf(-q0);
        float o = (qv > thr) ? qv : 0.f;
        outq[((size_t)(b * NN + n0 + j)) * 256 + l] = o;
        lsum += o;
    }
    atomicAdd(&staq[b * 256 + l], lsum);
}

// ---------------------------------------------------------------- k7: MLP head + BN + ReLU
__global__ __launch_bounds__(256) void k7_head(
    const float* __restrict__ spre, const float* __restrict__ staq,
    const float* __restrict__ f1w, const float* __restrict__ f2w,
    const float* __restrict__ ow, const float* __restrict__ og,
    const float* __restrict__ ob, const float* __restrict__ om,
    const float* __restrict__ ov, const float* __restrict__ gate,
    float* __restrict__ out0) {
    __shared__ float in0[16], in1[16];
    __shared__ float h1[16][64];
    __shared__ __align__(16) float h2[16][132];
    int tid = threadIdx.x;
    int lt = blockIdx.x, b = blockIdx.y;
    if (tid < 16) {
        int l = lt * 16 + tid;
        in0[tid] = gate[0] * (spre[b * 256 + l] * (1.f / 4608.f));
        in1[tid] = staq[b * 256 + l];
    }
    __syncthreads();
    for (int idx = tid; idx < 16 * 64; idx += 256) {
        int j = idx >> 6, o = idx & 63;
        float vv = f1w[o * 2] * in0[j] + f1w[o * 2 + 1] * in1[j];
        h1[j][o] = vv > 0.f ? vv : 0.01f * vv;
    }
    __syncthreads();
    for (int idx = tid; idx < 16 * 128; idx += 256) {
        int j = idx >> 7, o = idx & 127;
        float s = 0.f;
        for (int c = 0; c < 64; ++c) s += f2w[o * 64 + c] * h1[j][c];
        h2[j][o] = fmaxf(s, 0.f);
    }
    __syncthreads();
    {
        int o = tid;
        float acc[16];
#pragma unroll
        for (int j = 0; j < 16; ++j) acc[j] = 0.f;
        for (int c4 = 0; c4 < 128; c4 += 4) {
            float4 w4 = *(const float4*)&ow[(size_t)o * 128 + c4];
#pragma unroll
            for (int j = 0; j < 16; ++j) {
                float4 hh = *(const float4*)&h2[j][c4];
                acc[j] += w4.x * hh.x + w4.y * hh.y + w4.z * hh.z + w4.w * hh.w;
            }
        }
        float sc = og[o] / sqrtf(ov[o] + 1e-5f);
        float bo = ob[o] - om[o] * sc;
        float res[16];
#pragma unroll
        for (int j = 0; j < 16; ++j) { float vv = acc[j] * sc + bo; res[j] = fmaxf(vv, 0.f); }
        float* dst = &out0[((size_t)b * 256 + o) * 256 + lt * 16];
#pragma unroll
        for (int q = 0; q < 4; ++q)
            ((float4*)dst)[q] = make_float4(res[q * 4], res[q * 4 + 1], res[q * 4 + 2], res[q * 4 + 3]);
    }
}

// ----------------------------------------------------------------
extern "C" void kernel_launch(void* const* d_in, const int* in_sizes, int n_in,
                              void* d_out, int out_size, void* d_ws, size_t ws_size,
                              hipStream_t stream) {
    const float* x       = (const float*)d_in[0];
    const float* conv1_w = (const float*)d_in[1];
    const float* bn1_g   = (const float*)d_in[2];
    const float* bn1_b   = (const float*)d_in[3];
    const float* bn1_m   = (const float*)d_in[4];
    const float* bn1_v   = (const float*)d_in[5];
    const float* ln_g    = (const float*)d_in[6];
    const float* ln_b    = (const float*)d_in[7];
    const float* qkv_w   = (const float*)d_in[8];
    const float* qkv_b   = (const float*)d_in[9];
    const float* proj_w  = (const float*)d_in[10];
    const float* proj_b  = (const float*)d_in[11];
    const float* rpe     = (const float*)d_in[12];
    const float* conv2_w = (const float*)d_in[13];
    const float* f1_w    = (const float*)d_in[14];
    const float* f2_w    = (const float*)d_in[15];
    const float* out_w   = (const float*)d_in[16];
    const float* obn_g   = (const float*)d_in[17];
    const float* obn_b   = (const float*)d_in[18];
    const float* obn_m   = (const float*)d_in[19];
    const float* obn_v   = (const float*)d_in[20];
    const float* gate    = (const float*)d_in[21];
    float* wsf  = (float*)d_ws;
    float* out0 = (float*)d_out;
    float* outq = out0 + 1048576;

    hipMemsetAsync(wsf + OFF_SPRE, 0, (size_t)(OFF_BMIN - OFF_SPRE) * 4, stream);
    hipMemsetAsync(wsf + OFF_BMIN, 0xFF, 16 * 4, stream);

    hipLaunchKernelGGL(k0_prep, dim3(1), dim3(256), 0, stream, qkv_w, qkv_b, proj_w, proj_b, wsf);
    hipLaunchKernelGGL(k1_conv, dim3(9, 8, 16), dim3(256), 0, stream,
                       x, conv1_w, bn1_g, bn1_b, bn1_m, bn1_v, wsf + OFF_X1);
    hipLaunchKernelGGL(k4_cs, dim3(36, 16), dim3(256), 0, stream,
                       wsf + OFF_X1, conv2_w, wsf + OFF_CS, wsf + OFF_BSUM,
                       (unsigned*)(wsf + OFF_BMIN), (unsigned*)(wsf + OFF_BMAX));
    hipLaunchKernelGGL(k5_mom, dim3(36, 16), dim3(256), 0, stream,
                       wsf + OFF_CS, wsf + OFF_BSUM, wsf + OFF_BM2, wsf + OFF_BM4);
    hipLaunchKernelGGL(k5b_par, dim3(1), dim3(64), 0, stream,
                       wsf + OFF_BSUM, wsf + OFF_BM2, wsf + OFF_BM4,
                       (const unsigned*)(wsf + OFF_BMIN), (const unsigned*)(wsf + OFF_BMAX),
                       wsf + OFF_PAR);
    hipLaunchKernelGGL(k3_attn, dim3(196, 16), dim3(256), 0, stream,
                       wsf + OFF_X1, ln_g, ln_b, qkv_w, qkv_b, rpe, wsf, wsf + OFF_SPRE);
    hipLaunchKernelGGL(k6_quant, dim3(144, 16), dim3(256), 0, stream,
                       wsf + OFF_CS, wsf + OFF_PAR, outq, wsf + OFF_STAQ);
    hipLaunchKernelGGL(k7_head, dim3(16, 16), dim3(256), 0, stream,
                       wsf + OFF_SPRE, wsf + OFF_STAQ, f1_w, f2_w, out_w,
                       obn_g, obn_b, obn_m, obn_v, gate, out0);
}

// Round 3
// 1709.285 us; speedup vs baseline: 1.6480x; 1.6480x over previous
//
#include <hip/hip_runtime.h>
#include <math.h>

typedef unsigned short u16;
typedef short bf16x8 __attribute__((ext_vector_type(8)));
typedef float f32x4 __attribute__((ext_vector_type(4)));
typedef unsigned int uint4v __attribute__((ext_vector_type(4)));

// Shapes
#define NN   9216          // 96*96
#define CCH  128
#define LL   256

// Workspace layout (float offsets)
#define OFF_X1   0                 // 16*128*9216 = 18874368
#define OFF_CS   18874368          // 16*9216    = 147456
#define OFF_SPRE 19021824          // 4096  (zeroed)
#define OFF_STAQ 19025920          // 4096  (zeroed)
#define OFF_BSUM 19030016          // 16    (zeroed)
#define OFF_BM2  19030032          // 16    (zeroed)
#define OFF_BM4  19030048          // 16    (zeroed)
#define OFF_BMAX 19030064          // 16 uint (zeroed; cs>0 so 0 is safe identity)
#define OFF_BMIN 19030080          // 16 uint (0xFFFFFFFF)
#define OFF_PAR  19030096          // 64: per-b {absK, cmin, range, thresh}
#define OFF_WV   19030160          // 2*128 folded V weights
#define OFF_BV   19030416          // 2
#define OFF_PBS  19030418          // 1

__device__ __forceinline__ unsigned rne16(float f) {
    unsigned u = __float_as_uint(f);
    return (u + 0x7FFFu + ((u >> 16) & 1u)) >> 16;
}
__device__ __forceinline__ bf16x8 as_bf16x8(uint4v u) {
    union { uint4v u; bf16x8 b; } c; c.u = u; return c.b;
}

// ---------------------------------------------------------------- k0: fold proj/V path (attention)
__global__ void k0_prep(const float* __restrict__ qkv_w, const float* __restrict__ qkv_b,
                        const float* __restrict__ proj_w, const float* __restrict__ proj_b,
                        float* __restrict__ wsf) {
    __shared__ float psum[128];
    int t = threadIdx.x;
    if (t < 128) {
        float s = 0.f;
        for (int c = 0; c < 128; ++c) s += proj_w[c * 128 + t];
        psum[t] = s;
    }
    __syncthreads();
    {   // wv[h][c] = sum_j qkv_w[256+h*64+j][c] * psum[h*64+j]
        int h = t >> 7, c = t & 127;
        float s = 0.f;
        for (int j = 0; j < 64; ++j)
            s += qkv_w[(size_t)(256 + h * 64 + j) * 128 + c] * psum[h * 64 + j];
        wsf[OFF_WV + h * 128 + c] = s;
    }
    if (t < 2) {
        float s = 0.f;
        for (int j = 0; j < 64; ++j) s += qkv_b[256 + t * 64 + j] * psum[t * 64 + j];
        wsf[OFF_BV + t] = s;
    }
    if (t == 0) {
        float s = 0.f;
        for (int c = 0; c < 128; ++c) s += proj_b[c];
        wsf[OFF_PBS] = s;
    }
}

// ---------------------------------------------------------------- k0c: split conv weights (BN-folded) into 3 bf16 planes
// Layout idx = (((t*8 + icb)*8 + nfg)*64 + lane)*8 + j
//   value = conv1_w[oc=nfg*16+(lane&15)][ic=icb*32+(lane>>4)*8+j][tap t] * sc[oc]
__global__ __launch_bounds__(256) void k0c_wsplit(
    const float* __restrict__ w, const float* __restrict__ g, const float* __restrict__ bb,
    const float* __restrict__ m, const float* __restrict__ v,
    u16* __restrict__ bsh, u16* __restrict__ bsm, u16* __restrict__ bsl,
    float* __restrict__ bo) {
    int idx = blockIdx.x * 256 + threadIdx.x;   // 0 .. 294911
    int j    = idx & 7;
    int lane = (idx >> 3) & 63;
    int nfg  = (idx >> 9) & 7;
    int icb  = (idx >> 12) & 7;
    int t    = idx >> 15;
    int oc = nfg * 16 + (lane & 15);
    int ic = icb * 32 + ((lane >> 4) << 3) + j;
    float sc = g[oc] / sqrtf(v[oc] + 1e-5f);
    float wv = w[(size_t)(oc * 256 + ic) * 9 + t] * sc;
    unsigned hb = rne16(wv);
    float hf = __uint_as_float(hb << 16);
    float r1 = wv - hf;
    unsigned mb = rne16(r1);
    float mfv = __uint_as_float(mb << 16);
    float r2 = r1 - mfv;
    unsigned lb = rne16(r2);
    bsh[idx] = (u16)hb;
    bsm[idx] = (u16)mb;
    bsl[idx] = (u16)lb;
    if (blockIdx.x == 0 && threadIdx.x < 128) {
        int o = threadIdx.x;
        float s2 = g[o] / sqrtf(v[o] + 1e-5f);
        bo[o] = bb[o] - m[o] * s2;
    }
}

// ---------------------------------------------------------------- k1: conv3x3 via MFMA bf16 triple-split
// Tile: 8 rows x 16 cols spatial (M=128 as 8 M-frags of one spatial row), all 128 oc.
// 4 waves: wm = px-half (4 rows), wn = oc-half (64 oc). Grid (72, 16).
__global__ __launch_bounds__(256) void k1_mfma(
    const float* __restrict__ x,
    const u16* __restrict__ bsh, const u16* __restrict__ bsm, const u16* __restrict__ bsl,
    const float* __restrict__ bo,
    float* __restrict__ x1) {
    __shared__ unsigned pHM[10 * 18 * 36];   // [(row*18+col)*36 + ic] : (mid<<16)|hi
    __shared__ unsigned pL [10 * 18 * 36];   // lo in low16
    int tid = threadIdx.x;
    int lane = tid & 63, wave = tid >> 6;
    int wm = wave >> 1, wn = wave & 1;
    int l15 = lane & 15, lg = lane >> 4;
    int tile = blockIdx.x, b = blockIdx.y;
    int y0 = (tile / 6) * 8, x0 = (tile % 6) * 16;
    const float* xb = x + (size_t)b * 256 * NN;

    f32x4 acc[4][4];
#pragma unroll
    for (int mf = 0; mf < 4; ++mf)
#pragma unroll
        for (int nf = 0; nf < 4; ++nf) acc[mf][nf] = (f32x4){0.f, 0.f, 0.f, 0.f};

    for (int icb = 0; icb < 8; ++icb) {
        __syncthreads();
        // stage 10x18 halo patch x 32 ic, split into hi/mid/lo bf16
        for (int idx = tid; idx < 5760; idx += 256) {
            int ic = idx / 180;
            int rem = idx - ic * 180;
            int row = rem / 18, col = rem - row * 18;
            int gy = y0 - 1 + row, gx = x0 - 1 + col;
            float vv = 0.f;
            if (gy >= 0 && gy < 96 && gx >= 0 && gx < 96)
                vv = xb[(size_t)(icb * 32 + ic) * NN + gy * 96 + gx];
            unsigned hb = rne16(vv);
            float hf = __uint_as_float(hb << 16);
            float r1 = vv - hf;
            unsigned mb = rne16(r1);
            float mfv = __uint_as_float(mb << 16);
            float r2 = r1 - mfv;
            unsigned lb = rne16(r2);
            pHM[rem * 36 + ic] = (mb << 16) | hb;
            pL [rem * 36 + ic] = lb;
        }
        __syncthreads();
#pragma unroll
        for (int t = 0; t < 9; ++t) {
            const int dy = t / 3, dx = t - dy * 3;
            // cache 12 B fragments for this (icb, tap)
            bf16x8 Bh[4], Bm[4], Bl[4];
#pragma unroll
            for (int nf = 0; nf < 4; ++nf) {
                size_t boff = ((((size_t)t * 8 + icb) * 8 + (wn * 4 + nf)) * 64 + lane) * 8;
                Bh[nf] = *(const bf16x8*)(bsh + boff);
                Bm[nf] = *(const bf16x8*)(bsm + boff);
                Bl[nf] = *(const bf16x8*)(bsl + boff);
            }
#pragma unroll
            for (int mf = 0; mf < 4; ++mf) {
                int base = ((wm * 4 + mf + dy) * 18 + dx + l15) * 36 + lg * 8;
                uint4v h0 = *(const uint4v*)&pHM[base];
                uint4v h1 = *(const uint4v*)&pHM[base + 4];
                uint4v l0 = *(const uint4v*)&pL[base];
                uint4v l1 = *(const uint4v*)&pL[base + 4];
                uint4v ah, am, al;
                ah.x = (h0.x & 0xFFFFu) | (h0.y << 16);
                ah.y = (h0.z & 0xFFFFu) | (h0.w << 16);
                ah.z = (h1.x & 0xFFFFu) | (h1.y << 16);
                ah.w = (h1.z & 0xFFFFu) | (h1.w << 16);
                am.x = (h0.x >> 16) | (h0.y & 0xFFFF0000u);
                am.y = (h0.z >> 16) | (h0.w & 0xFFFF0000u);
                am.z = (h1.x >> 16) | (h1.y & 0xFFFF0000u);
                am.w = (h1.z >> 16) | (h1.w & 0xFFFF0000u);
                al.x = (l0.x & 0xFFFFu) | (l0.y << 16);
                al.y = (l0.z & 0xFFFFu) | (l0.w << 16);
                al.z = (l1.x & 0xFFFFu) | (l1.y << 16);
                al.w = (l1.z & 0xFFFFu) | (l1.w << 16);
                bf16x8 Ah = as_bf16x8(ah), Am = as_bf16x8(am), Al = as_bf16x8(al);
#pragma unroll
                for (int nf = 0; nf < 4; ++nf) {
                    f32x4 a = acc[mf][nf];
                    a = __builtin_amdgcn_mfma_f32_16x16x32_bf16(Ah, Bh[nf], a, 0, 0, 0);
                    a = __builtin_amdgcn_mfma_f32_16x16x32_bf16(Am, Bh[nf], a, 0, 0, 0);
                    a = __builtin_amdgcn_mfma_f32_16x16x32_bf16(Ah, Bm[nf], a, 0, 0, 0);
                    a = __builtin_amdgcn_mfma_f32_16x16x32_bf16(Al, Bh[nf], a, 0, 0, 0);
                    a = __builtin_amdgcn_mfma_f32_16x16x32_bf16(Ah, Bl[nf], a, 0, 0, 0);
                    a = __builtin_amdgcn_mfma_f32_16x16x32_bf16(Am, Bm[nf], a, 0, 0, 0);
                    acc[mf][nf] = a;
                }
            }
        }
    }
    // epilogue: + bo, LeakyReLU, store float4 (4 consecutive px per lane)
#pragma unroll
    for (int nf = 0; nf < 4; ++nf) {
        int oc = wn * 64 + nf * 16 + l15;
        float bov = bo[oc];
#pragma unroll
        for (int mf = 0; mf < 4; ++mf) {
            int py = y0 + wm * 4 + mf;
            int px = x0 + lg * 4;
            float4 r;
            float t0;
            t0 = acc[mf][nf].x + bov; r.x = t0 > 0.f ? t0 : 0.01f * t0;
            t0 = acc[mf][nf].y + bov; r.y = t0 > 0.f ? t0 : 0.01f * t0;
            t0 = acc[mf][nf].z + bov; r.z = t0 > 0.f ? t0 : 0.01f * t0;
            t0 = acc[mf][nf].w + bov; r.w = t0 > 0.f ? t0 : 0.01f * t0;
            *(float4*)&x1[((size_t)b * 128 + oc) * NN + py * 96 + px] = r;
        }
    }
}

// ---------------------------------------------------------------- k3: windowed attention -> pooled s
__global__ __launch_bounds__(256) void k3_attn(
    const float* __restrict__ x1, const float* __restrict__ ln_g, const float* __restrict__ ln_b,
    const float* __restrict__ qkv_w, const float* __restrict__ qkv_b,
    const float* __restrict__ rpe, const float* __restrict__ wsf,
    float* __restrict__ spre) {
    __shared__ __align__(16) float T[49 * 132];   // tokens; reused as S[2][49][52]
    __shared__ __align__(16) float Qs[49 * 132];
    __shared__ __align__(16) float Ks[49 * 132];
    __shared__ float vps[49 * 2];
    __shared__ float mstat[49], rstat[49];
    int tid = threadIdx.x;
    int wwin = blockIdx.x, b = blockIdx.y;
    int wh = wwin / 14, ww = wwin % 14;

    for (int idx = tid; idx < 128 * 49; idx += 256) {
        int c = idx / 49, i = idx % 49;
        int th = wh * 7 + i / 7, tw = ww * 7 + i % 7;
        float vv = 0.f;
        if (th < 96 && tw < 96) vv = x1[((size_t)b * 128 + c) * NN + th * 96 + tw];
        T[i * 132 + c] = vv;
    }
    __syncthreads();
    if (tid < 49) {
        float s = 0.f;
        for (int c4 = 0; c4 < 128; c4 += 4) {
            float4 t4 = *(const float4*)&T[tid * 132 + c4];
            s += t4.x + t4.y + t4.z + t4.w;
        }
        float mean = s * (1.f / 128.f);
        float vs = 0.f;
        for (int c4 = 0; c4 < 128; c4 += 4) {
            float4 t4 = *(const float4*)&T[tid * 132 + c4];
            float d0 = t4.x - mean, d1 = t4.y - mean, d2 = t4.z - mean, d3 = t4.w - mean;
            vs += d0 * d0 + d1 * d1 + d2 * d2 + d3 * d3;
        }
        mstat[tid] = mean;
        rstat[tid] = 1.f / sqrtf(vs * (1.f / 128.f) + 1e-6f);
    }
    __syncthreads();
    for (int idx = tid; idx < 49 * 128; idx += 256) {
        int i = idx >> 7, c = idx & 127;
        int th = wh * 7 + i / 7, tw = ww * 7 + i % 7;
        float vv = T[i * 132 + c];
        float nv = (vv - mstat[i]) * rstat[i] * ln_g[c] + ln_b[c];
        T[i * 132 + c] = (th < 96 && tw < 96) ? nv : 0.f;
    }
    __syncthreads();
    {
        int o2 = (tid & 127) * 2;
        int i0 = (tid >> 7) * 24;
        float a0[25], a1[25];
#pragma unroll
        for (int ii = 0; ii < 25; ++ii) { a0[ii] = 0.f; a1[ii] = 0.f; }
        for (int cc = 0; cc < 128; cc += 4) {
            float4 wa = *(const float4*)&qkv_w[(size_t)o2 * 128 + cc];
            float4 wc = *(const float4*)&qkv_w[(size_t)(o2 + 1) * 128 + cc];
#pragma unroll
            for (int ii = 0; ii < 25; ++ii) {
                float4 t4 = *(const float4*)&T[(i0 + ii) * 132 + cc];
                a0[ii] += t4.x * wa.x + t4.y * wa.y + t4.z * wa.z + t4.w * wa.w;
                a1[ii] += t4.x * wc.x + t4.y * wc.y + t4.z * wc.z + t4.w * wc.w;
            }
        }
        float bq0 = qkv_b[o2], bq1 = qkv_b[o2 + 1];
        float* dst = (o2 < 128) ? Qs : Ks;
        int oo = o2 & 127;
#pragma unroll
        for (int ii = 0; ii < 25; ++ii) {
            dst[(i0 + ii) * 132 + oo]     = a0[ii] + bq0;
            dst[(i0 + ii) * 132 + oo + 1] = a1[ii] + bq1;
        }
    }
    if (tid < 98) {
        int i = tid >> 1, h = tid & 1;
        float s = wsf[OFF_BV + h];
        for (int c = 0; c < 128; ++c) s += T[i * 132 + c] * wsf[OFF_WV + h * 128 + c];
        vps[i * 2 + h] = s;
    }
    __syncthreads();
    {
        int h = tid >> 7, i = tid & 127;
        if (i < 49) {
            float qr[64];
#pragma unroll
            for (int d4 = 0; d4 < 64; d4 += 4) {
                float4 q4 = *(const float4*)&Qs[i * 132 + h * 64 + d4];
                qr[d4] = q4.x; qr[d4 + 1] = q4.y; qr[d4 + 2] = q4.z; qr[d4 + 3] = q4.w;
            }
            int ih7 = i / 7, iw7 = i % 7;
            for (int j = 0; j < 49; ++j) {
                float s = 0.f;
#pragma unroll
                for (int d4 = 0; d4 < 64; d4 += 4) {
                    float4 k4 = *(const float4*)&Ks[j * 132 + h * 64 + d4];
                    s += qr[d4] * k4.x + qr[d4 + 1] * k4.y + qr[d4 + 2] * k4.z + qr[d4 + 3] * k4.w;
                }
                int relidx = (ih7 - j / 7 + 6) * 13 + (iw7 - j % 7 + 6);
                T[(h * 49 + i) * 52 + j] = s * 0.125f + rpe[relidx * 2 + h];
            }
        }
    }
    __syncthreads();
    {
        int h = tid >> 7, i = tid & 127;
        if (i < 49) {
            float r[49];
            float* row = &T[(h * 49 + i) * 52];
#pragma unroll
            for (int j = 0; j < 49; ++j) r[j] = row[j];
            float mx = r[0];
#pragma unroll
            for (int j = 1; j < 49; ++j) mx = fmaxf(mx, r[j]);
            float sum = 0.f;
#pragma unroll
            for (int j = 0; j < 49; ++j) { r[j] = expf(r[j] - mx); sum += r[j]; }
            float inv = 1.f / sum;
#pragma unroll
            for (int j = 0; j < 49; ++j) row[j] = r[j] * inv;
        }
    }
    __syncthreads();
    if (tid < 49) {
        int i = tid;
        int th = wh * 7 + i / 7, tw = ww * 7 + i % 7;
        float s = wsf[OFF_PBS];
        for (int h = 0; h < 2; ++h)
            for (int j = 0; j < 49; ++j)
                s += T[(h * 49 + i) * 52 + j] * vps[j * 2 + h];
        if (th < 96 && tw < 96) {
            int l = (th * 96 + tw) / 36;
            atomicAdd(&spre[b * 256 + l], s);
        }
    }
}

// ---------------------------------------------------------------- k4: cs = sigmoid(conv2.x1), + sum/min/max
__global__ __launch_bounds__(256) void k4_cs(
    const float* __restrict__ x1, const float* __restrict__ w2,
    float* __restrict__ csb, float* __restrict__ bsum,
    unsigned* __restrict__ bmin, unsigned* __restrict__ bmax) {
    int b = blockIdx.y;
    int n = blockIdx.x * 256 + threadIdx.x;
    float s = 0.f;
    for (int c = 0; c < 128; ++c) s += w2[c] * x1[((size_t)b * 128 + c) * NN + n];
    float csv = 1.f / (1.f + expf(-s));
    csb[(size_t)b * NN + n] = csv;
    float ss = csv, mn = csv, mx = csv;
    for (int o = 32; o > 0; o >>= 1) {
        ss += __shfl_down(ss, o, 64);
        mn = fminf(mn, __shfl_down(mn, o, 64));
        mx = fmaxf(mx, __shfl_down(mx, o, 64));
    }
    if ((threadIdx.x & 63) == 0) {
        atomicAdd(&bsum[b], ss);
        atomicMin(&bmin[b], __float_as_uint(mn));
        atomicMax(&bmax[b], __float_as_uint(mx));
    }
}

// ---------------------------------------------------------------- k5: central moments
__global__ __launch_bounds__(256) void k5_mom(
    const float* __restrict__ csb, const float* __restrict__ bsum,
    float* __restrict__ bm2, float* __restrict__ bm4) {
    int b = blockIdx.y;
    int n = blockIdx.x * 256 + threadIdx.x;
    float mu = bsum[b] * (1.f / 9216.f);
    float d = csb[(size_t)b * NN + n] - mu;
    float d2 = d * d, d4 = d2 * d2;
    for (int o = 32; o > 0; o >>= 1) {
        d2 += __shfl_down(d2, o, 64);
        d4 += __shfl_down(d4, o, 64);
    }
    if ((threadIdx.x & 63) == 0) { atomicAdd(&bm2[b], d2); atomicAdd(&bm4[b], d4); }
}

// ---------------------------------------------------------------- k5b: per-b params
__global__ void k5b_par(const float* __restrict__ bsum, const float* __restrict__ bm2,
                        const float* __restrict__ bm4, const unsigned* __restrict__ bmin,
                        const unsigned* __restrict__ bmax, float* __restrict__ par) {
    int b = threadIdx.x;
    if (b >= 16) return;
    float n = 9216.f;
    float m2 = bm2[b], m4 = bm4[b];
    float var = m2 / (n - 1.f);
    float t1 = n * (n + 1.f) / ((n - 1.f) * (n - 2.f) * (n - 3.f)) * m4 / (var * var);
    float t2 = 3.f * ((n - 1.f) * (n - 1.f)) / ((n - 2.f) * (n - 3.f));
    float kurt = t1 - t2;
    float cmin = __uint_as_float(bmin[b]);
    float cmax = __uint_as_float(bmax[b]);
    float range = cmax - cmin;
    float ql0 = (1.f / 512.f) * range + cmin;   // reference op order
    float ql1 = (3.f / 512.f) * range + cmin;
    float inter = ql1 - ql0;
    par[b * 4 + 0] = fabsf(kurt);
    par[b * 4 + 1] = cmin;
    par[b * 4 + 2] = range;
    par[b * 4 + 3] = 1.f - inter;
}

// ---------------------------------------------------------------- k6: quant output + sta sums
__global__ __launch_bounds__(256) void k6_quant(
    const float* __restrict__ csb, const float* __restrict__ par,
    float* __restrict__ outq, float* __restrict__ staq) {
    int b = blockIdx.y;
    int n0 = blockIdx.x * 64;
    int l = threadIdx.x;
    float absK = par[b * 4 + 0], cmin = par[b * 4 + 1];
    float range = par[b * 4 + 2], thr = par[b * 4 + 3];
    float qlv = ((float)(2 * l + 1) * (1.f / 512.f)) * range + cmin;
    float lsum = 0.f;
    for (int j = 0; j < 64; ++j) {
        float csv = csb[(size_t)b * NN + n0 + j];
        float d = fabsf(qlv - csv);
        float q0 = 1.f - d;
        float qv = absK * expf(-q0);
        float o = (qv > thr) ? qv : 0.f;
        outq[((size_t)(b * NN + n0 + j)) * 256 + l] = o;
        lsum += o;
    }
    atomicAdd(&staq[b * 256 + l], lsum);
}

// ---------------------------------------------------------------- k7: MLP head + BN + ReLU
__global__ __launch_bounds__(256) void k7_head(
    const float* __restrict__ spre, const float* __restrict__ staq,
    const float* __restrict__ f1w, const float* __restrict__ f2w,
    const float* __restrict__ ow, const float* __restrict__ og,
    const float* __restrict__ ob, const float* __restrict__ om,
    const float* __restrict__ ov, const float* __restrict__ gate,
    float* __restrict__ out0) {
    __shared__ float in0[16], in1[16];
    __shared__ float h1[16][64];
    __shared__ __align__(16) float h2[16][132];
    int tid = threadIdx.x;
    int lt = blockIdx.x, b = blockIdx.y;
    if (tid < 16) {
        int l = lt * 16 + tid;
        in0[tid] = gate[0] * (spre[b * 256 + l] * (1.f / 4608.f));
        in1[tid] = staq[b * 256 + l];
    }
    __syncthreads();
    for (int idx = tid; idx < 16 * 64; idx += 256) {
        int j = idx >> 6, o = idx & 63;
        float vv = f1w[o * 2] * in0[j] + f1w[o * 2 + 1] * in1[j];
        h1[j][o] = vv > 0.f ? vv : 0.01f * vv;
    }
    __syncthreads();
    for (int idx = tid; idx < 16 * 128; idx += 256) {
        int j = idx >> 7, o = idx & 127;
        float s = 0.f;
        for (int c = 0; c < 64; ++c) s += f2w[o * 64 + c] * h1[j][c];
        h2[j][o] = fmaxf(s, 0.f);
    }
    __syncthreads();
    {
        int o = tid;
        float acc[16];
#pragma unroll
        for (int j = 0; j < 16; ++j) acc[j] = 0.f;
        for (int c4 = 0; c4 < 128; c4 += 4) {
            float4 w4 = *(const float4*)&ow[(size_t)o * 128 + c4];
#pragma unroll
            for (int j = 0; j < 16; ++j) {
                float4 hh = *(const float4*)&h2[j][c4];
                acc[j] += w4.x * hh.x + w4.y * hh.y + w4.z * hh.z + w4.w * hh.w;
            }
        }
        float sc = og[o] / sqrtf(ov[o] + 1e-5f);
        float bo = ob[o] - om[o] * sc;
        float res[16];
#pragma unroll
        for (int j = 0; j < 16; ++j) { float vv = acc[j] * sc + bo; res[j] = fmaxf(vv, 0.f); }
        float* dst = &out0[((size_t)b * 256 + o) * 256 + lt * 16];
#pragma unroll
        for (int q = 0; q < 4; ++q)
            ((float4*)dst)[q] = make_float4(res[q * 4], res[q * 4 + 1], res[q * 4 + 2], res[q * 4 + 3]);
    }
}

// ----------------------------------------------------------------
extern "C" void kernel_launch(void* const* d_in, const int* in_sizes, int n_in,
                              void* d_out, int out_size, void* d_ws, size_t ws_size,
                              hipStream_t stream) {
    const float* x       = (const float*)d_in[0];
    const float* conv1_w = (const float*)d_in[1];
    const float* bn1_g   = (const float*)d_in[2];
    const float* bn1_b   = (const float*)d_in[3];
    const float* bn1_m   = (const float*)d_in[4];
    const float* bn1_v   = (const float*)d_in[5];
    const float* ln_g    = (const float*)d_in[6];
    const float* ln_b    = (const float*)d_in[7];
    const float* qkv_w   = (const float*)d_in[8];
    const float* qkv_b   = (const float*)d_in[9];
    const float* proj_w  = (const float*)d_in[10];
    const float* proj_b  = (const float*)d_in[11];
    const float* rpe     = (const float*)d_in[12];
    const float* conv2_w = (const float*)d_in[13];
    const float* f1_w    = (const float*)d_in[14];
    const float* f2_w    = (const float*)d_in[15];
    const float* out_w   = (const float*)d_in[16];
    const float* obn_g   = (const float*)d_in[17];
    const float* obn_b   = (const float*)d_in[18];
    const float* obn_m   = (const float*)d_in[19];
    const float* obn_v   = (const float*)d_in[20];
    const float* gate    = (const float*)d_in[21];
    float* wsf  = (float*)d_ws;
    float* out0 = (float*)d_out;
    float* outq = out0 + 1048576;

    // Weight-split scratch lives in the quant region of d_out:
    // written by k0c, consumed by k1_mfma, fully overwritten later by k6.
    u16* bsh = (u16*)outq;             // 294912 u16
    u16* bsm = bsh + 294912;
    u16* bsl = bsm + 294912;
    float* bo = (float*)(bsl + 294912);  // 128 floats

    hipMemsetAsync(wsf + OFF_SPRE, 0, (size_t)(OFF_BMIN - OFF_SPRE) * 4, stream);
    hipMemsetAsync(wsf + OFF_BMIN, 0xFF, 16 * 4, stream);

    hipLaunchKernelGGL(k0_prep, dim3(1), dim3(256), 0, stream, qkv_w, qkv_b, proj_w, proj_b, wsf);
    hipLaunchKernelGGL(k0c_wsplit, dim3(1152), dim3(256), 0, stream,
                       conv1_w, bn1_g, bn1_b, bn1_m, bn1_v, bsh, bsm, bsl, bo);
    hipLaunchKernelGGL(k1_mfma, dim3(72, 16), dim3(256), 0, stream,
                       x, bsh, bsm, bsl, bo, wsf + OFF_X1);
    hipLaunchKernelGGL(k4_cs, dim3(36, 16), dim3(256), 0, stream,
                       wsf + OFF_X1, conv2_w, wsf + OFF_CS, wsf + OFF_BSUM,
                       (unsigned*)(wsf + OFF_BMIN), (unsigned*)(wsf + OFF_BMAX));
    hipLaunchKernelGGL(k5_mom, dim3(36, 16), dim3(256), 0, stream,
                       wsf + OFF_CS, wsf + OFF_BSUM, wsf + OFF_BM2, wsf + OFF_BM4);
    hipLaunchKernelGGL(k5b_par, dim3(1), dim3(64), 0, stream,
                       wsf + OFF_BSUM, wsf + OFF_BM2, wsf + OFF_BM4,
                       (const unsigned*)(wsf + OFF_BMIN), (const unsigned*)(wsf + OFF_BMAX),
                       wsf + OFF_PAR);
    hipLaunchKernelGGL(k3_attn, dim3(196, 16), dim3(256), 0, stream,
                       wsf + OFF_X1, ln_g, ln_b, qkv_w, qkv_b, rpe, wsf, wsf + OFF_SPRE);
    hipLaunchKernelGGL(k6_quant, dim3(144, 16), dim3(256), 0, stream,
                       wsf + OFF_CS, wsf + OFF_PAR, outq, wsf + OFF_STAQ);
    hipLaunchKernelGGL(k7_head, dim3(16, 16), dim3(256), 0, stream,
                       wsf + OFF_SPRE, wsf + OFF_STAQ, f1_w, f2_w, out_w,
                       obn_g, obn_b, obn_m, obn_v, gate, out0);
}

// Round 4
// 1277.807 us; speedup vs baseline: 2.2045x; 1.3377x over previous
//
#include <hip/hip_runtime.h>
#include <math.h>

typedef unsigned short u16;
typedef short bf16x8 __attribute__((ext_vector_type(8)));
typedef float f32x4 __attribute__((ext_vector_type(4)));
typedef unsigned int uint4v __attribute__((ext_vector_type(4)));

// Shapes
#define NN   9216          // 96*96
#define CCH  128
#define LL   256

// Workspace layout (float offsets)
#define OFF_X1   0                 // 16*128*9216 = 18874368
#define OFF_CS   18874368          // 16*9216    = 147456
#define OFF_SPRE 19021824          // 4096  (zeroed)
#define OFF_STAQ 19025920          // 4096  (zeroed)
#define OFF_BSUM 19030016          // 16    (zeroed)
#define OFF_BM2  19030032          // 16    (zeroed)
#define OFF_BM4  19030048          // 16    (zeroed)
#define OFF_BMAX 19030064          // 16 uint (zeroed; cs>0 so 0 is safe identity)
#define OFF_BMIN 19030080          // 16 uint (0xFFFFFFFF)
#define OFF_PAR  19030096          // 64: per-b {absK, cmin, range, thresh}
#define OFF_WV   19030160          // 2*128 folded V weights
#define OFF_BV   19030416          // 2
#define OFF_PBS  19030418          // 1

#define PSTR 104                   // u16 per staged pixel: 4 icgrp * 3 planes * 8 + 8 pad (bank stride 52w ≡ 20 mod 32 -> 2-way)

__device__ __forceinline__ unsigned rne16(float f) {
    unsigned u = __float_as_uint(f);
    return (u + 0x7FFFu + ((u >> 16) & 1u)) >> 16;
}

// ---------------------------------------------------------------- k0: fold proj/V path (attention)
__global__ void k0_prep(const float* __restrict__ qkv_w, const float* __restrict__ qkv_b,
                        const float* __restrict__ proj_w, const float* __restrict__ proj_b,
                        float* __restrict__ wsf) {
    __shared__ float psum[128];
    int t = threadIdx.x;
    if (t < 128) {
        float s = 0.f;
        for (int c = 0; c < 128; ++c) s += proj_w[c * 128 + t];
        psum[t] = s;
    }
    __syncthreads();
    {   // wv[h][c] = sum_j qkv_w[256+h*64+j][c] * psum[h*64+j]
        int h = t >> 7, c = t & 127;
        float s = 0.f;
        for (int j = 0; j < 64; ++j)
            s += qkv_w[(size_t)(256 + h * 64 + j) * 128 + c] * psum[h * 64 + j];
        wsf[OFF_WV + h * 128 + c] = s;
    }
    if (t < 2) {
        float s = 0.f;
        for (int j = 0; j < 64; ++j) s += qkv_b[256 + t * 64 + j] * psum[t * 64 + j];
        wsf[OFF_BV + t] = s;
    }
    if (t == 0) {
        float s = 0.f;
        for (int c = 0; c < 128; ++c) s += proj_b[c];
        wsf[OFF_PBS] = s;
    }
}

// ---------------------------------------------------------------- k0c: split conv weights (BN-folded) into 3 bf16 planes
// Layout idx = (((t*8 + icb)*8 + nfg)*64 + lane)*8 + j
//   value = conv1_w[oc=nfg*16+(lane&15)][ic=icb*32+(lane>>4)*8+j][tap t] * sc[oc]
__global__ __launch_bounds__(256) void k0c_wsplit(
    const float* __restrict__ w, const float* __restrict__ g, const float* __restrict__ bb,
    const float* __restrict__ m, const float* __restrict__ v,
    u16* __restrict__ bsh, u16* __restrict__ bsm, u16* __restrict__ bsl,
    float* __restrict__ bo) {
    int idx = blockIdx.x * 256 + threadIdx.x;   // 0 .. 294911
    int j    = idx & 7;
    int lane = (idx >> 3) & 63;
    int nfg  = (idx >> 9) & 7;
    int icb  = (idx >> 12) & 7;
    int t    = idx >> 15;
    int oc = nfg * 16 + (lane & 15);
    int ic = icb * 32 + ((lane >> 4) << 3) + j;
    float sc = g[oc] / sqrtf(v[oc] + 1e-5f);
    float wv = w[(size_t)(oc * 256 + ic) * 9 + t] * sc;
    unsigned hb = rne16(wv);
    float hf = __uint_as_float(hb << 16);
    float r1 = wv - hf;
    unsigned mb = rne16(r1);
    float mfv = __uint_as_float(mb << 16);
    float r2 = r1 - mfv;
    unsigned lb = rne16(r2);
    bsh[idx] = (u16)hb;
    bsm[idx] = (u16)mb;
    bsl[idx] = (u16)lb;
    if (blockIdx.x == 0 && threadIdx.x < 128) {
        int o = threadIdx.x;
        float s2 = g[o] / sqrtf(v[o] + 1e-5f);
        bo[o] = bb[o] - m[o] * s2;
    }
}

// ---------------------------------------------------------------- k1: conv3x3 via MFMA bf16 triple-split
// Tile: 8 rows x 16 cols spatial, 64 oc per block (ocg selects which 64).
// 4 waves: wm = row-half (4 rows), wn = oc-half (32 oc). Grid (72, 2, 16).
// LDS: one u16 array, pos-major; per pos: 4 icgrp x {hi,mid,lo} x 8 -> direct bf16x8 reads, no repack.
__global__ __launch_bounds__(256) void k1_mfma(
    const float* __restrict__ x,
    const u16* __restrict__ bsh, const u16* __restrict__ bsm, const u16* __restrict__ bsl,
    const float* __restrict__ bo,
    float* __restrict__ x1) {
    __shared__ __align__(16) u16 P[10 * 18 * PSTR];   // 37440 B
    int tid = threadIdx.x;
    int lane = tid & 63, wave = tid >> 6;
    int wm = wave >> 1, wn = wave & 1;
    int l15 = lane & 15, lg = lane >> 4;
    int tile = blockIdx.x, ocg = blockIdx.y, b = blockIdx.z;
    int y0 = (tile / 6) * 8, x0 = (tile % 6) * 16;
    const float* xb = x + (size_t)b * 256 * NN;

    // staging coords: threads 0..179 each own one halo pixel (row,col)
    int srow = tid / 18, scol = tid - srow * 18;
    int gy = y0 - 1 + srow, gx = x0 - 1 + scol;
    bool sval = (tid < 180) && gy >= 0 && gy < 96 && gx >= 0 && gx < 96;
    const float* pbase = xb + (size_t)(gy >= 0 ? (gy < 96 ? gy : 95) : 0) * 96
                            + (gx >= 0 ? (gx < 96 ? gx : 95) : 0);
    int pb = tid * PSTR;

    f32x4 acc[4][2];
#pragma unroll
    for (int mf = 0; mf < 4; ++mf)
#pragma unroll
        for (int nf = 0; nf < 2; ++nf) acc[mf][nf] = (f32x4){0.f, 0.f, 0.f, 0.f};

    int nfg0 = ocg * 4 + wn * 2;

    for (int icb = 0; icb < 8; ++icb) {
        __syncthreads();
        if (tid < 180) {
            const float* pic = pbase + (size_t)icb * 32 * NN;
#pragma unroll
            for (int g = 0; g < 4; ++g) {
                unsigned hw[4], mw[4], lw[4];
#pragma unroll
                for (int jj = 0; jj < 4; ++jj) {
                    float v0 = sval ? pic[(size_t)(g * 8 + 2 * jj) * NN] : 0.f;
                    float v1 = sval ? pic[(size_t)(g * 8 + 2 * jj + 1) * NN] : 0.f;
                    unsigned h0 = rne16(v0); float hf0 = __uint_as_float(h0 << 16);
                    float r0 = v0 - hf0;     unsigned m0 = rne16(r0);
                    float mf0 = __uint_as_float(m0 << 16);
                    unsigned l0 = rne16(r0 - mf0);
                    unsigned h1 = rne16(v1); float hf1 = __uint_as_float(h1 << 16);
                    float r1 = v1 - hf1;     unsigned m1 = rne16(r1);
                    float mf1 = __uint_as_float(m1 << 16);
                    unsigned l1 = rne16(r1 - mf1);
                    hw[jj] = h0 | (h1 << 16);
                    mw[jj] = m0 | (m1 << 16);
                    lw[jj] = l0 | (l1 << 16);
                }
                *(uint4v*)&P[pb + (g * 3 + 0) * 8] = (uint4v){hw[0], hw[1], hw[2], hw[3]};
                *(uint4v*)&P[pb + (g * 3 + 1) * 8] = (uint4v){mw[0], mw[1], mw[2], mw[3]};
                *(uint4v*)&P[pb + (g * 3 + 2) * 8] = (uint4v){lw[0], lw[1], lw[2], lw[3]};
            }
        }
        __syncthreads();
#pragma unroll
        for (int t = 0; t < 9; ++t) {
            const int dy = t / 3, dx = t - dy * 3;
            bf16x8 Bh[2], Bm[2], Bl[2];
#pragma unroll
            for (int nf = 0; nf < 2; ++nf) {
                size_t boff = ((((size_t)t * 8 + icb) * 8 + (nfg0 + nf)) * 64 + lane) * 8;
                Bh[nf] = *(const bf16x8*)(bsh + boff);
                Bm[nf] = *(const bf16x8*)(bsm + boff);
                Bl[nf] = *(const bf16x8*)(bsl + boff);
            }
#pragma unroll
            for (int mf = 0; mf < 4; ++mf) {
                int abase = ((wm * 4 + mf + dy) * 18 + dx + l15) * PSTR + lg * 24;
                bf16x8 Ah = *(const bf16x8*)&P[abase];
                bf16x8 Am = *(const bf16x8*)&P[abase + 8];
                bf16x8 Al = *(const bf16x8*)&P[abase + 16];
#pragma unroll
                for (int nf = 0; nf < 2; ++nf) {
                    f32x4 a = acc[mf][nf];
                    a = __builtin_amdgcn_mfma_f32_16x16x32_bf16(Ah, Bh[nf], a, 0, 0, 0);
                    a = __builtin_amdgcn_mfma_f32_16x16x32_bf16(Am, Bh[nf], a, 0, 0, 0);
                    a = __builtin_amdgcn_mfma_f32_16x16x32_bf16(Ah, Bm[nf], a, 0, 0, 0);
                    a = __builtin_amdgcn_mfma_f32_16x16x32_bf16(Al, Bh[nf], a, 0, 0, 0);
                    a = __builtin_amdgcn_mfma_f32_16x16x32_bf16(Ah, Bl[nf], a, 0, 0, 0);
                    a = __builtin_amdgcn_mfma_f32_16x16x32_bf16(Am, Bm[nf], a, 0, 0, 0);
                    acc[mf][nf] = a;
                }
            }
        }
    }
    // epilogue: + bo, LeakyReLU, store float4 (4 consecutive px per lane)
#pragma unroll
    for (int nf = 0; nf < 2; ++nf) {
        int oc = ocg * 64 + wn * 32 + nf * 16 + l15;
        float bov = bo[oc];
#pragma unroll
        for (int mf = 0; mf < 4; ++mf) {
            int py = y0 + wm * 4 + mf;
            int px = x0 + lg * 4;
            float4 r;
            float t0;
            t0 = acc[mf][nf].x + bov; r.x = t0 > 0.f ? t0 : 0.01f * t0;
            t0 = acc[mf][nf].y + bov; r.y = t0 > 0.f ? t0 : 0.01f * t0;
            t0 = acc[mf][nf].z + bov; r.z = t0 > 0.f ? t0 : 0.01f * t0;
            t0 = acc[mf][nf].w + bov; r.w = t0 > 0.f ? t0 : 0.01f * t0;
            *(float4*)&x1[((size_t)b * 128 + oc) * NN + py * 96 + px] = r;
        }
    }
}

// ---------------------------------------------------------------- k3: windowed attention -> pooled s
__global__ __launch_bounds__(256) void k3_attn(
    const float* __restrict__ x1, const float* __restrict__ ln_g, const float* __restrict__ ln_b,
    const float* __restrict__ qkv_w, const float* __restrict__ qkv_b,
    const float* __restrict__ rpe, const float* __restrict__ wsf,
    float* __restrict__ spre) {
    __shared__ __align__(16) float T[49 * 132];   // tokens; reused as S[2][49][52]
    __shared__ __align__(16) float Qs[49 * 132];
    __shared__ __align__(16) float Ks[49 * 132];
    __shared__ float vps[49 * 2];
    __shared__ float mstat[49], rstat[49];
    int tid = threadIdx.x;
    int wwin = blockIdx.x, b = blockIdx.y;
    int wh = wwin / 14, ww = wwin % 14;

    for (int idx = tid; idx < 128 * 49; idx += 256) {
        int c = idx / 49, i = idx % 49;
        int th = wh * 7 + i / 7, tw = ww * 7 + i % 7;
        float vv = 0.f;
        if (th < 96 && tw < 96) vv = x1[((size_t)b * 128 + c) * NN + th * 96 + tw];
        T[i * 132 + c] = vv;
    }
    __syncthreads();
    if (tid < 49) {
        float s = 0.f;
        for (int c4 = 0; c4 < 128; c4 += 4) {
            float4 t4 = *(const float4*)&T[tid * 132 + c4];
            s += t4.x + t4.y + t4.z + t4.w;
        }
        float mean = s * (1.f / 128.f);
        float vs = 0.f;
        for (int c4 = 0; c4 < 128; c4 += 4) {
            float4 t4 = *(const float4*)&T[tid * 132 + c4];
            float d0 = t4.x - mean, d1 = t4.y - mean, d2 = t4.z - mean, d3 = t4.w - mean;
            vs += d0 * d0 + d1 * d1 + d2 * d2 + d3 * d3;
        }
        mstat[tid] = mean;
        rstat[tid] = 1.f / sqrtf(vs * (1.f / 128.f) + 1e-6f);
    }
    __syncthreads();
    for (int idx = tid; idx < 49 * 128; idx += 256) {
        int i = idx >> 7, c = idx & 127;
        int th = wh * 7 + i / 7, tw = ww * 7 + i % 7;
        float vv = T[i * 132 + c];
        float nv = (vv - mstat[i]) * rstat[i] * ln_g[c] + ln_b[c];
        T[i * 132 + c] = (th < 96 && tw < 96) ? nv : 0.f;
    }
    __syncthreads();
    {
        int o2 = (tid & 127) * 2;
        int i0 = (tid >> 7) * 24;
        float a0[25], a1[25];
#pragma unroll
        for (int ii = 0; ii < 25; ++ii) { a0[ii] = 0.f; a1[ii] = 0.f; }
        for (int cc = 0; cc < 128; cc += 4) {
            float4 wa = *(const float4*)&qkv_w[(size_t)o2 * 128 + cc];
            float4 wc = *(const float4*)&qkv_w[(size_t)(o2 + 1) * 128 + cc];
#pragma unroll
            for (int ii = 0; ii < 25; ++ii) {
                float4 t4 = *(const float4*)&T[(i0 + ii) * 132 + cc];
                a0[ii] += t4.x * wa.x + t4.y * wa.y + t4.z * wa.z + t4.w * wa.w;
                a1[ii] += t4.x * wc.x + t4.y * wc.y + t4.z * wc.z + t4.w * wc.w;
            }
        }
        float bq0 = qkv_b[o2], bq1 = qkv_b[o2 + 1];
        float* dst = (o2 < 128) ? Qs : Ks;
        int oo = o2 & 127;
#pragma unroll
        for (int ii = 0; ii < 25; ++ii) {
            dst[(i0 + ii) * 132 + oo]     = a0[ii] + bq0;
            dst[(i0 + ii) * 132 + oo + 1] = a1[ii] + bq1;
        }
    }
    if (tid < 98) {
        int i = tid >> 1, h = tid & 1;
        float s = wsf[OFF_BV + h];
        for (int c = 0; c < 128; ++c) s += T[i * 132 + c] * wsf[OFF_WV + h * 128 + c];
        vps[i * 2 + h] = s;
    }
    __syncthreads();
    {
        int h = tid >> 7, i = tid & 127;
        if (i < 49) {
            float qr[64];
#pragma unroll
            for (int d4 = 0; d4 < 64; d4 += 4) {
                float4 q4 = *(const float4*)&Qs[i * 132 + h * 64 + d4];
                qr[d4] = q4.x; qr[d4 + 1] = q4.y; qr[d4 + 2] = q4.z; qr[d4 + 3] = q4.w;
            }
            int ih7 = i / 7, iw7 = i % 7;
            for (int j = 0; j < 49; ++j) {
                float s = 0.f;
#pragma unroll
                for (int d4 = 0; d4 < 64; d4 += 4) {
                    float4 k4 = *(const float4*)&Ks[j * 132 + h * 64 + d4];
                    s += qr[d4] * k4.x + qr[d4 + 1] * k4.y + qr[d4 + 2] * k4.z + qr[d4 + 3] * k4.w;
                }
                int relidx = (ih7 - j / 7 + 6) * 13 + (iw7 - j % 7 + 6);
                T[(h * 49 + i) * 52 + j] = s * 0.125f + rpe[relidx * 2 + h];
            }
        }
    }
    __syncthreads();
    {
        int h = tid >> 7, i = tid & 127;
        if (i < 49) {
            float r[49];
            float* row = &T[(h * 49 + i) * 52];
#pragma unroll
            for (int j = 0; j < 49; ++j) r[j] = row[j];
            float mx = r[0];
#pragma unroll
            for (int j = 1; j < 49; ++j) mx = fmaxf(mx, r[j]);
            float sum = 0.f;
#pragma unroll
            for (int j = 0; j < 49; ++j) { r[j] = expf(r[j] - mx); sum += r[j]; }
            float inv = 1.f / sum;
#pragma unroll
            for (int j = 0; j < 49; ++j) row[j] = r[j] * inv;
        }
    }
    __syncthreads();
    if (tid < 49) {
        int i = tid;
        int th = wh * 7 + i / 7, tw = ww * 7 + i % 7;
        float s = wsf[OFF_PBS];
        for (int h = 0; h < 2; ++h)
            for (int j = 0; j < 49; ++j)
                s += T[(h * 49 + i) * 52 + j] * vps[j * 2 + h];
        if (th < 96 && tw < 96) {
            int l = (th * 96 + tw) / 36;
            atomicAdd(&spre[b * 256 + l], s);
        }
    }
}

// ---------------------------------------------------------------- k4: cs = sigmoid(conv2.x1), + sum/min/max
__global__ __launch_bounds__(256) void k4_cs(
    const float* __restrict__ x1, const float* __restrict__ w2,
    float* __restrict__ csb, float* __restrict__ bsum,
    unsigned* __restrict__ bmin, unsigned* __restrict__ bmax) {
    int b = blockIdx.y;
    int n = blockIdx.x * 256 + threadIdx.x;
    float s = 0.f;
    for (int c = 0; c < 128; ++c) s += w2[c] * x1[((size_t)b * 128 + c) * NN + n];
    float csv = 1.f / (1.f + expf(-s));
    csb[(size_t)b * NN + n] = csv;
    float ss = csv, mn = csv, mx = csv;
    for (int o = 32; o > 0; o >>= 1) {
        ss += __shfl_down(ss, o, 64);
        mn = fminf(mn, __shfl_down(mn, o, 64));
        mx = fmaxf(mx, __shfl_down(mx, o, 64));
    }
    if ((threadIdx.x & 63) == 0) {
        atomicAdd(&bsum[b], ss);
        atomicMin(&bmin[b], __float_as_uint(mn));
        atomicMax(&bmax[b], __float_as_uint(mx));
    }
}

// ---------------------------------------------------------------- k5: central moments
__global__ __launch_bounds__(256) void k5_mom(
    const float* __restrict__ csb, const float* __restrict__ bsum,
    float* __restrict__ bm2, float* __restrict__ bm4) {
    int b = blockIdx.y;
    int n = blockIdx.x * 256 + threadIdx.x;
    float mu = bsum[b] * (1.f / 9216.f);
    float d = csb[(size_t)b * NN + n] - mu;
    float d2 = d * d, d4 = d2 * d2;
    for (int o = 32; o > 0; o >>= 1) {
        d2 += __shfl_down(d2, o, 64);
        d4 += __shfl_down(d4, o, 64);
    }
    if ((threadIdx.x & 63) == 0) { atomicAdd(&bm2[b], d2); atomicAdd(&bm4[b], d4); }
}

// ---------------------------------------------------------------- k5b: per-b params
__global__ void k5b_par(const float* __restrict__ bsum, const float* __restrict__ bm2,
                        const float* __restrict__ bm4, const unsigned* __restrict__ bmin,
                        const unsigned* __restrict__ bmax, float* __restrict__ par) {
    int b = threadIdx.x;
    if (b >= 16) return;
    float n = 9216.f;
    float m2 = bm2[b], m4 = bm4[b];
    float var = m2 / (n - 1.f);
    float t1 = n * (n + 1.f) / ((n - 1.f) * (n - 2.f) * (n - 3.f)) * m4 / (var * var);
    float t2 = 3.f * ((n - 1.f) * (n - 1.f)) / ((n - 2.f) * (n - 3.f));
    float kurt = t1 - t2;
    float cmin = __uint_as_float(bmin[b]);
    float cmax = __uint_as_float(bmax[b]);
    float range = cmax - cmin;
    float ql0 = (1.f / 512.f) * range + cmin;   // reference op order
    float ql1 = (3.f / 512.f) * range + cmin;
    float inter = ql1 - ql0;
    par[b * 4 + 0] = fabsf(kurt);
    par[b * 4 + 1] = cmin;
    par[b * 4 + 2] = range;
    par[b * 4 + 3] = 1.f - inter;
}

// ---------------------------------------------------------------- k6: quant output + sta sums
__global__ __launch_bounds__(256) void k6_quant(
    const float* __restrict__ csb, const float* __restrict__ par,
    float* __restrict__ outq, float* __restrict__ staq) {
    int b = blockIdx.y;
    int n0 = blockIdx.x * 64;
    int l = threadIdx.x;
    float absK = par[b * 4 + 0], cmin = par[b * 4 + 1];
    float range = par[b * 4 + 2], thr = par[b * 4 + 3];
    float qlv = ((float)(2 * l + 1) * (1.f / 512.f)) * range + cmin;
    float lsum = 0.f;
    for (int j = 0; j < 64; ++j) {
        float csv = csb[(size_t)b * NN + n0 + j];
        float d = fabsf(qlv - csv);
        float q0 = 1.f - d;
        float qv = absK * expf(-q0);
        float o = (qv > thr) ? qv : 0.f;
        outq[((size_t)(b * NN + n0 + j)) * 256 + l] = o;
        lsum += o;
    }
    atomicAdd(&staq[b * 256 + l], lsum);
}

// ---------------------------------------------------------------- k7: MLP head + BN + ReLU
__global__ __launch_bounds__(256) void k7_head(
    const float* __restrict__ spre, const float* __restrict__ staq,
    const float* __restrict__ f1w, const float* __restrict__ f2w,
    const float* __restrict__ ow, const float* __restrict__ og,
    const float* __restrict__ ob, const float* __restrict__ om,
    const float* __restrict__ ov, const float* __restrict__ gate,
    float* __restrict__ out0) {
    __shared__ float in0[16], in1[16];
    __shared__ float h1[16][64];
    __shared__ __align__(16) float h2[16][132];
    int tid = threadIdx.x;
    int lt = blockIdx.x, b = blockIdx.y;
    if (tid < 16) {
        int l = lt * 16 + tid;
        in0[tid] = gate[0] * (spre[b * 256 + l] * (1.f / 4608.f));
        in1[tid] = staq[b * 256 + l];
    }
    __syncthreads();
    for (int idx = tid; idx < 16 * 64; idx += 256) {
        int j = idx >> 6, o = idx & 63;
        float vv = f1w[o * 2] * in0[j] + f1w[o * 2 + 1] * in1[j];
        h1[j][o] = vv > 0.f ? vv : 0.01f * vv;
    }
    __syncthreads();
    for (int idx = tid; idx < 16 * 128; idx += 256) {
        int j = idx >> 7, o = idx & 127;
        float s = 0.f;
        for (int c = 0; c < 64; ++c) s += f2w[o * 64 + c] * h1[j][c];
        h2[j][o] = fmaxf(s, 0.f);
    }
    __syncthreads();
    {
        int o = tid;
        float acc[16];
#pragma unroll
        for (int j = 0; j < 16; ++j) acc[j] = 0.f;
        for (int c4 = 0; c4 < 128; c4 += 4) {
            float4 w4 = *(const float4*)&ow[(size_t)o * 128 + c4];
#pragma unroll
            for (int j = 0; j < 16; ++j) {
                float4 hh = *(const float4*)&h2[j][c4];
                acc[j] += w4.x * hh.x + w4.y * hh.y + w4.z * hh.z + w4.w * hh.w;
            }
        }
        float sc = og[o] / sqrtf(ov[o] + 1e-5f);
        float bo = ob[o] - om[o] * sc;
        float res[16];
#pragma unroll
        for (int j = 0; j < 16; ++j) { float vv = acc[j] * sc + bo; res[j] = fmaxf(vv, 0.f); }
        float* dst = &out0[((size_t)b * 256 + o) * 256 + lt * 16];
#pragma unroll
        for (int q = 0; q < 4; ++q)
            ((float4*)dst)[q] = make_float4(res[q * 4], res[q * 4 + 1], res[q * 4 + 2], res[q * 4 + 3]);
    }
}

// ----------------------------------------------------------------
extern "C" void kernel_launch(void* const* d_in, const int* in_sizes, int n_in,
                              void* d_out, int out_size, void* d_ws, size_t ws_size,
                              hipStream_t stream) {
    const float* x       = (const float*)d_in[0];
    const float* conv1_w = (const float*)d_in[1];
    const float* bn1_g   = (const float*)d_in[2];
    const float* bn1_b   = (const float*)d_in[3];
    const float* bn1_m   = (const float*)d_in[4];
    const float* bn1_v   = (const float*)d_in[5];
    const float* ln_g    = (const float*)d_in[6];
    const float* ln_b    = (const float*)d_in[7];
    const float* qkv_w   = (const float*)d_in[8];
    const float* qkv_b   = (const float*)d_in[9];
    const float* proj_w  = (const float*)d_in[10];
    const float* proj_b  = (const float*)d_in[11];
    const float* rpe     = (const float*)d_in[12];
    const float* conv2_w = (const float*)d_in[13];
    const float* f1_w    = (const float*)d_in[14];
    const float* f2_w    = (const float*)d_in[15];
    const float* out_w   = (const float*)d_in[16];
    const float* obn_g   = (const float*)d_in[17];
    const float* obn_b   = (const float*)d_in[18];
    const float* obn_m   = (const float*)d_in[19];
    const float* obn_v   = (const float*)d_in[20];
    const float* gate    = (const float*)d_in[21];
    float* wsf  = (float*)d_ws;
    float* out0 = (float*)d_out;
    float* outq = out0 + 1048576;

    // Weight-split scratch lives in the quant region of d_out:
    // written by k0c, consumed by k1_mfma, fully overwritten later by k6.
    u16* bsh = (u16*)outq;             // 294912 u16
    u16* bsm = bsh + 294912;
    u16* bsl = bsm + 294912;
    float* bo = (float*)(bsl + 294912);  // 128 floats

    hipMemsetAsync(wsf + OFF_SPRE, 0, (size_t)(OFF_BMIN - OFF_SPRE) * 4, stream);
    hipMemsetAsync(wsf + OFF_BMIN, 0xFF, 16 * 4, stream);

    hipLaunchKernelGGL(k0_prep, dim3(1), dim3(256), 0, stream, qkv_w, qkv_b, proj_w, proj_b, wsf);
    hipLaunchKernelGGL(k0c_wsplit, dim3(1152), dim3(256), 0, stream,
                       conv1_w, bn1_g, bn1_b, bn1_m, bn1_v, bsh, bsm, bsl, bo);
    hipLaunchKernelGGL(k1_mfma, dim3(72, 2, 16), dim3(256), 0, stream,
                       x, bsh, bsm, bsl, bo, wsf + OFF_X1);
    hipLaunchKernelGGL(k4_cs, dim3(36, 16), dim3(256), 0, stream,
                       wsf + OFF_X1, conv2_w, wsf + OFF_CS, wsf + OFF_BSUM,
                       (unsigned*)(wsf + OFF_BMIN), (unsigned*)(wsf + OFF_BMAX));
    hipLaunchKernelGGL(k5_mom, dim3(36, 16), dim3(256), 0, stream,
                       wsf + OFF_CS, wsf + OFF_BSUM, wsf + OFF_BM2, wsf + OFF_BM4);
    hipLaunchKernelGGL(k5b_par, dim3(1), dim3(64), 0, stream,
                       wsf + OFF_BSUM, wsf + OFF_BM2, wsf + OFF_BM4,
                       (const unsigned*)(wsf + OFF_BMIN), (const unsigned*)(wsf + OFF_BMAX),
                       wsf + OFF_PAR);
    hipLaunchKernelGGL(k3_attn, dim3(196, 16), dim3(256), 0, stream,
                       wsf + OFF_X1, ln_g, ln_b, qkv_w, qkv_b, rpe, wsf, wsf + OFF_SPRE);
    hipLaunchKernelGGL(k6_quant, dim3(144, 16), dim3(256), 0, stream,
                       wsf + OFF_CS, wsf + OFF_PAR, outq, wsf + OFF_STAQ);
    hipLaunchKernelGGL(k7_head, dim3(16, 16), dim3(256), 0, stream,
                       wsf + OFF_SPRE, wsf + OFF_STAQ, f1_w, f2_w, out_w,
                       obn_g, obn_b, obn_m, obn_v, gate, out0);
}

// Round 5
// 1053.228 us; speedup vs baseline: 2.6746x; 1.2132x over previous
//
#include <hip/hip_runtime.h>
#include <math.h>

typedef unsigned short u16;
typedef short bf16x8 __attribute__((ext_vector_type(8)));
typedef float f32x4 __attribute__((ext_vector_type(4)));
typedef unsigned int uint4v __attribute__((ext_vector_type(4)));

// Shapes
#define NN   9216          // 96*96
#define CCH  128
#define LL   256

// Workspace layout (float offsets)
#define OFF_X1   0                 // 16*128*9216 = 18874368
#define OFF_CS   18874368          // 16*9216    = 147456
#define OFF_SPRE 19021824          // 4096  (zeroed)
#define OFF_STAQ 19025920          // 4096  (zeroed)
#define OFF_BSUM 19030016          // 16    (zeroed)
#define OFF_BM2  19030032          // 16    (zeroed)
#define OFF_BM4  19030048          // 16    (zeroed)
#define OFF_BMAX 19030064          // 16 uint (zeroed; cs>0 so 0 is safe identity)
#define OFF_BMIN 19030080          // 16 uint (0xFFFFFFFF)
#define OFF_PAR  19030096          // 64: per-b {absK, cmin, range, thresh}
#define OFF_WV   19030160          // 2*128 folded V weights
#define OFF_BV   19030416          // 2
#define OFF_PBS  19030418          // 1
#define OFF_WQK  19030432          // 32768 u16 = 16384 floats: qkv_w rows 0..255 as bf16 B-fragments

#define PSTR 104                   // k1 LDS stride (u16) per staged pixel

__device__ __forceinline__ unsigned rne16(float f) {
    unsigned u = __float_as_uint(f);
    return (u + 0x7FFFu + ((u >> 16) & 1u)) >> 16;
}

// ---------------------------------------------------------------- k0: fold proj/V path + qkv bf16 B-fragments
__global__ void k0_prep(const float* __restrict__ qkv_w, const float* __restrict__ qkv_b,
                        const float* __restrict__ proj_w, const float* __restrict__ proj_b,
                        float* __restrict__ wsf) {
    __shared__ float psum[128];
    int t = threadIdx.x;
    if (t < 128) {
        float s = 0.f;
        for (int c = 0; c < 128; ++c) s += proj_w[c * 128 + t];
        psum[t] = s;
    }
    __syncthreads();
    {   // wv[h][c] = sum_j qkv_w[256+h*64+j][c] * psum[h*64+j]
        int h = t >> 7, c = t & 127;
        float s = 0.f;
        for (int j = 0; j < 64; ++j)
            s += qkv_w[(size_t)(256 + h * 64 + j) * 128 + c] * psum[h * 64 + j];
        wsf[OFF_WV + h * 128 + c] = s;
    }
    if (t < 2) {
        float s = 0.f;
        for (int j = 0; j < 64; ++j) s += qkv_b[256 + t * 64 + j] * psum[t * 64 + j];
        wsf[OFF_BV + t] = s;
    }
    if (t == 0) {
        float s = 0.f;
        for (int c = 0; c < 128; ++c) s += proj_b[c];
        wsf[OFF_PBS] = s;
    }
    // Wqk[(ks*16+ng)*64+lane][8]: bf16(qkv_w[ng*16+(lane&15)][ks*32+(lane>>4)*8+j])
    u16* wqk = (u16*)(wsf + OFF_WQK);
    for (int idx = t; idx < 32768; idx += 256) {
        int j = idx & 7;
        int lane = (idx >> 3) & 63;
        int ng = (idx >> 9) & 15;
        int ks = idx >> 13;
        int och = ng * 16 + (lane & 15);        // 0..255 (q rows then k rows of qkv_w)
        int c = ks * 32 + ((lane >> 4) << 3) + j;
        wqk[idx] = (u16)rne16(qkv_w[(size_t)och * 128 + c]);
    }
}

// ---------------------------------------------------------------- k0c: split conv weights (BN-folded) into 3 bf16 planes
__global__ __launch_bounds__(256) void k0c_wsplit(
    const float* __restrict__ w, const float* __restrict__ g, const float* __restrict__ bb,
    const float* __restrict__ m, const float* __restrict__ v,
    u16* __restrict__ bsh, u16* __restrict__ bsm, u16* __restrict__ bsl,
    float* __restrict__ bo) {
    int idx = blockIdx.x * 256 + threadIdx.x;   // 0 .. 294911
    int j    = idx & 7;
    int lane = (idx >> 3) & 63;
    int nfg  = (idx >> 9) & 7;
    int icb  = (idx >> 12) & 7;
    int t    = idx >> 15;
    int oc = nfg * 16 + (lane & 15);
    int ic = icb * 32 + ((lane >> 4) << 3) + j;
    float sc = g[oc] / sqrtf(v[oc] + 1e-5f);
    float wv = w[(size_t)(oc * 256 + ic) * 9 + t] * sc;
    unsigned hb = rne16(wv);
    float hf = __uint_as_float(hb << 16);
    float r1 = wv - hf;
    unsigned mb = rne16(r1);
    float mfv = __uint_as_float(mb << 16);
    float r2 = r1 - mfv;
    unsigned lb = rne16(r2);
    bsh[idx] = (u16)hb;
    bsm[idx] = (u16)mb;
    bsl[idx] = (u16)lb;
    if (blockIdx.x == 0 && threadIdx.x < 128) {
        int o = threadIdx.x;
        float s2 = g[o] / sqrtf(v[o] + 1e-5f);
        bo[o] = bb[o] - m[o] * s2;
    }
}

// ---------------------------------------------------------------- k1: conv3x3 via MFMA bf16 triple-split (unchanged round-4)
__global__ __launch_bounds__(256) void k1_mfma(
    const float* __restrict__ x,
    const u16* __restrict__ bsh, const u16* __restrict__ bsm, const u16* __restrict__ bsl,
    const float* __restrict__ bo,
    float* __restrict__ x1) {
    __shared__ __align__(16) u16 P[10 * 18 * PSTR];
    int tid = threadIdx.x;
    int lane = tid & 63, wave = tid >> 6;
    int wm = wave >> 1, wn = wave & 1;
    int l15 = lane & 15, lg = lane >> 4;
    int tile = blockIdx.x, ocg = blockIdx.y, b = blockIdx.z;
    int y0 = (tile / 6) * 8, x0 = (tile % 6) * 16;
    const float* xb = x + (size_t)b * 256 * NN;

    int srow = tid / 18, scol = tid - srow * 18;
    int gy = y0 - 1 + srow, gx = x0 - 1 + scol;
    bool sval = (tid < 180) && gy >= 0 && gy < 96 && gx >= 0 && gx < 96;
    const float* pbase = xb + (size_t)(gy >= 0 ? (gy < 96 ? gy : 95) : 0) * 96
                            + (gx >= 0 ? (gx < 96 ? gx : 95) : 0);
    int pb = tid * PSTR;

    f32x4 acc[4][2];
#pragma unroll
    for (int mf = 0; mf < 4; ++mf)
#pragma unroll
        for (int nf = 0; nf < 2; ++nf) acc[mf][nf] = (f32x4){0.f, 0.f, 0.f, 0.f};

    int nfg0 = ocg * 4 + wn * 2;

    for (int icb = 0; icb < 8; ++icb) {
        __syncthreads();
        if (tid < 180) {
            const float* pic = pbase + (size_t)icb * 32 * NN;
#pragma unroll
            for (int g = 0; g < 4; ++g) {
                unsigned hw[4], mw[4], lw[4];
#pragma unroll
                for (int jj = 0; jj < 4; ++jj) {
                    float v0 = sval ? pic[(size_t)(g * 8 + 2 * jj) * NN] : 0.f;
                    float v1 = sval ? pic[(size_t)(g * 8 + 2 * jj + 1) * NN] : 0.f;
                    unsigned h0 = rne16(v0); float hf0 = __uint_as_float(h0 << 16);
                    float r0 = v0 - hf0;     unsigned m0 = rne16(r0);
                    float mf0 = __uint_as_float(m0 << 16);
                    unsigned l0 = rne16(r0 - mf0);
                    unsigned h1 = rne16(v1); float hf1 = __uint_as_float(h1 << 16);
                    float r1 = v1 - hf1;     unsigned m1 = rne16(r1);
                    float mf1 = __uint_as_float(m1 << 16);
                    unsigned l1 = rne16(r1 - mf1);
                    hw[jj] = h0 | (h1 << 16);
                    mw[jj] = m0 | (m1 << 16);
                    lw[jj] = l0 | (l1 << 16);
                }
                *(uint4v*)&P[pb + (g * 3 + 0) * 8] = (uint4v){hw[0], hw[1], hw[2], hw[3]};
                *(uint4v*)&P[pb + (g * 3 + 1) * 8] = (uint4v){mw[0], mw[1], mw[2], mw[3]};
                *(uint4v*)&P[pb + (g * 3 + 2) * 8] = (uint4v){lw[0], lw[1], lw[2], lw[3]};
            }
        }
        __syncthreads();
#pragma unroll
        for (int t = 0; t < 9; ++t) {
            const int dy = t / 3, dx = t - dy * 3;
            bf16x8 Bh[2], Bm[2], Bl[2];
#pragma unroll
            for (int nf = 0; nf < 2; ++nf) {
                size_t boff = ((((size_t)t * 8 + icb) * 8 + (nfg0 + nf)) * 64 + lane) * 8;
                Bh[nf] = *(const bf16x8*)(bsh + boff);
                Bm[nf] = *(const bf16x8*)(bsm + boff);
                Bl[nf] = *(const bf16x8*)(bsl + boff);
            }
#pragma unroll
            for (int mf = 0; mf < 4; ++mf) {
                int abase = ((wm * 4 + mf + dy) * 18 + dx + l15) * PSTR + lg * 24;
                bf16x8 Ah = *(const bf16x8*)&P[abase];
                bf16x8 Am = *(const bf16x8*)&P[abase + 8];
                bf16x8 Al = *(const bf16x8*)&P[abase + 16];
#pragma unroll
                for (int nf = 0; nf < 2; ++nf) {
                    f32x4 a = acc[mf][nf];
                    a = __builtin_amdgcn_mfma_f32_16x16x32_bf16(Ah, Bh[nf], a, 0, 0, 0);
                    a = __builtin_amdgcn_mfma_f32_16x16x32_bf16(Am, Bh[nf], a, 0, 0, 0);
                    a = __builtin_amdgcn_mfma_f32_16x16x32_bf16(Ah, Bm[nf], a, 0, 0, 0);
                    a = __builtin_amdgcn_mfma_f32_16x16x32_bf16(Al, Bh[nf], a, 0, 0, 0);
                    a = __builtin_amdgcn_mfma_f32_16x16x32_bf16(Ah, Bl[nf], a, 0, 0, 0);
                    a = __builtin_amdgcn_mfma_f32_16x16x32_bf16(Am, Bm[nf], a, 0, 0, 0);
                    acc[mf][nf] = a;
                }
            }
        }
    }
#pragma unroll
    for (int nf = 0; nf < 2; ++nf) {
        int oc = ocg * 64 + wn * 32 + nf * 16 + l15;
        float bov = bo[oc];
#pragma unroll
        for (int mf = 0; mf < 4; ++mf) {
            int py = y0 + wm * 4 + mf;
            int px = x0 + lg * 4;
            float4 r;
            float t0;
            t0 = acc[mf][nf].x + bov; r.x = t0 > 0.f ? t0 : 0.01f * t0;
            t0 = acc[mf][nf].y + bov; r.y = t0 > 0.f ? t0 : 0.01f * t0;
            t0 = acc[mf][nf].z + bov; r.z = t0 > 0.f ? t0 : 0.01f * t0;
            t0 = acc[mf][nf].w + bov; r.w = t0 > 0.f ? t0 : 0.01f * t0;
            *(float4*)&x1[((size_t)b * 128 + oc) * NN + py * 96 + px] = r;
        }
    }
}

// ---------------------------------------------------------------- k3 v2: windowed attention via MFMA
// Per block: one 7x7 window. LN fp32 -> T bf16[64][136] -> QKV MFMA (bf16) -> Q,K bf16 LDS
// -> logits MFMA -> S fp32 (+rpe) -> softmax -> collapsed V/proj pooling.
__global__ __launch_bounds__(256) void k3_attn(
    const float* __restrict__ x1, const float* __restrict__ ln_g, const float* __restrict__ ln_b,
    const float* __restrict__ qkv_b, const float* __restrict__ rpe,
    const float* __restrict__ wsf, float* __restrict__ spre) {
    __shared__ __align__(16) float SM[49 * 132];     // staging Xw fp32, later S[2][49][52]
    __shared__ __align__(16) u16 Ts[64 * 136];
    __shared__ __align__(16) u16 Qs[64 * 136];
    __shared__ __align__(16) u16 Ks[64 * 136];
    __shared__ float vps[49 * 2];
    __shared__ float mstat[49], rstat[49];
    __shared__ float rpe_s[338];
    int tid = threadIdx.x;
    int lane = tid & 63, wave = tid >> 6;
    int l15 = lane & 15, lg = lane >> 4;
    int wwin = blockIdx.x, b = blockIdx.y;
    int wh = wwin / 14, ww = wwin % 14;
    const u16* wqk = (const u16*)(wsf + OFF_WQK);

    // ---- stage x1 window (fp32) + rpe
    for (int idx = tid; idx < 128 * 49; idx += 256) {
        int c = idx / 49, i = idx - c * 49;
        int th = wh * 7 + (i * 37 >> 8), tw = ww * 7 + (i - (i * 37 >> 8) * 7);
        float vv = 0.f;
        if (th < 96 && tw < 96) vv = x1[((size_t)b * 128 + c) * NN + th * 96 + tw];
        SM[i * 132 + c] = vv;
    }
    if (tid < 338) rpe_s[tid] = rpe[tid];
    __syncthreads();
    // ---- LN stats: 4 lanes per token
    if (tid < 196) {
        int i = tid >> 2, p = tid & 3;
        float s = 0.f;
        for (int c4 = 0; c4 < 32; c4 += 4) {
            float4 t4 = *(const float4*)&SM[i * 132 + p * 32 + c4];
            s += t4.x + t4.y + t4.z + t4.w;
        }
        s += __shfl_xor(s, 1, 64);
        s += __shfl_xor(s, 2, 64);
        float mean = s * (1.f / 128.f);
        float vs = 0.f;
        for (int c4 = 0; c4 < 32; c4 += 4) {
            float4 t4 = *(const float4*)&SM[i * 132 + p * 32 + c4];
            float d0 = t4.x - mean, d1 = t4.y - mean, d2 = t4.z - mean, d3 = t4.w - mean;
            vs += d0 * d0 + d1 * d1 + d2 * d2 + d3 * d3;
        }
        vs += __shfl_xor(vs, 1, 64);
        vs += __shfl_xor(vs, 2, 64);
        if (p == 0) {
            mstat[i] = mean;
            rstat[i] = 1.f / sqrtf(vs * (1.f / 128.f) + 1e-6f);
        }
    }
    __syncthreads();
    // ---- write normalized tokens as bf16 into Ts (pad rows/invalid tokens = 0)
    for (int idx = tid; idx < 64 * 128; idx += 256) {
        int i = idx >> 7, c = idx & 127;
        u16 out = 0;
        if (i < 49) {
            int i7 = i * 37 >> 8;
            int th = wh * 7 + i7, tw = ww * 7 + (i - i7 * 7);
            if (th < 96 && tw < 96) {
                float nv = (SM[i * 132 + c] - mstat[i]) * rstat[i] * ln_g[c] + ln_b[c];
                out = (u16)rne16(nv);
            }
        }
        Ts[i * 136 + c] = out;
    }
    __syncthreads();
    // ---- QKV MFMA: wave w -> out channels w*64..w*64+63 (waves 0,1 = Q; 2,3 = K)
    {
        f32x4 qacc[4][4];
#pragma unroll
        for (int mf = 0; mf < 4; ++mf)
#pragma unroll
            for (int nf = 0; nf < 4; ++nf) qacc[mf][nf] = (f32x4){0.f, 0.f, 0.f, 0.f};
        for (int ks = 0; ks < 4; ++ks) {
            bf16x8 Bv[4];
#pragma unroll
            for (int nf = 0; nf < 4; ++nf)
                Bv[nf] = *(const bf16x8*)&wqk[(((size_t)ks * 16 + wave * 4 + nf) * 64 + lane) * 8];
#pragma unroll
            for (int mf = 0; mf < 4; ++mf) {
                bf16x8 Av = *(const bf16x8*)&Ts[(mf * 16 + l15) * 136 + ks * 32 + lg * 8];
#pragma unroll
                for (int nf = 0; nf < 4; ++nf)
                    qacc[mf][nf] = __builtin_amdgcn_mfma_f32_16x16x32_bf16(Av, Bv[nf], qacc[mf][nf], 0, 0, 0);
            }
        }
#pragma unroll
        for (int nf = 0; nf < 4; ++nf) {
            int och = wave * 64 + nf * 16 + l15;      // 0..255
            float bias = qkv_b[och];
            u16* dst = (och < 128) ? Qs : Ks;
            int ch = och & 127;
#pragma unroll
            for (int mf = 0; mf < 4; ++mf) {
#pragma unroll
                for (int r = 0; r < 4; ++r) {
                    int tok = mf * 16 + lg * 4 + r;
                    dst[tok * 136 + ch] = (u16)rne16(qacc[mf][nf][r] + bias);
                }
            }
        }
    }
    // ---- vps[i][h] from bf16 T (post-LN)
    if (tid < 98) {
        int i = tid >> 1, h = tid & 1;
        float s = wsf[OFF_BV + h];
        for (int c = 0; c < 128; ++c)
            s += __uint_as_float((unsigned)Ts[i * 136 + c] << 16) * wsf[OFF_WV + h * 128 + c];
        vps[i * 2 + h] = s;
    }
    __syncthreads();
    // ---- logits MFMA: wave -> (head = w>>1, j-half = w&1); S = qk/8 + rpe
    {
        int h = wave >> 1, jh = wave & 1;
        f32x4 sacc[4][2];
#pragma unroll
        for (int mf = 0; mf < 4; ++mf)
#pragma unroll
            for (int nf = 0; nf < 2; ++nf) sacc[mf][nf] = (f32x4){0.f, 0.f, 0.f, 0.f};
        for (int ks = 0; ks < 2; ++ks) {
            bf16x8 Bv[2];
#pragma unroll
            for (int nf = 0; nf < 2; ++nf)
                Bv[nf] = *(const bf16x8*)&Ks[(jh * 32 + nf * 16 + l15) * 136 + h * 64 + ks * 32 + lg * 8];
#pragma unroll
            for (int mf = 0; mf < 4; ++mf) {
                bf16x8 Av = *(const bf16x8*)&Qs[(mf * 16 + l15) * 136 + h * 64 + ks * 32 + lg * 8];
#pragma unroll
                for (int nf = 0; nf < 2; ++nf)
                    sacc[mf][nf] = __builtin_amdgcn_mfma_f32_16x16x32_bf16(Av, Bv[nf], sacc[mf][nf], 0, 0, 0);
            }
        }
        __syncthreads();   // SM (staging) free for S now
#pragma unroll
        for (int nf = 0; nf < 2; ++nf) {
            int j = jh * 32 + nf * 16 + l15;
            if (j < 49) {
                int j7 = j * 37 >> 8, jm = j - j7 * 7;
#pragma unroll
                for (int mf = 0; mf < 4; ++mf) {
#pragma unroll
                    for (int r = 0; r < 4; ++r) {
                        int i = mf * 16 + lg * 4 + r;
                        if (i < 49) {
                            int i7 = i * 37 >> 8, im = i - i7 * 7;
                            int rel = (i7 - j7 + 6) * 13 + (im - jm + 6);
                            SM[(h * 49 + i) * 52 + j] = sacc[mf][nf][r] * 0.125f + rpe_s[rel * 2 + h];
                        }
                    }
                }
            }
        }
    }
    __syncthreads();
    // ---- softmax per row
    if (tid < 98) {
        int h = tid / 49, i = tid - h * 49;
        float r[49];
        float* row = &SM[(h * 49 + i) * 52];
#pragma unroll
        for (int j = 0; j < 49; ++j) r[j] = row[j];
        float mx = r[0];
#pragma unroll
        for (int j = 1; j < 49; ++j) mx = fmaxf(mx, r[j]);
        float sum = 0.f;
#pragma unroll
        for (int j = 0; j < 49; ++j) { r[j] = expf(r[j] - mx); sum += r[j]; }
        float inv = 1.f / sum;
#pragma unroll
        for (int j = 0; j < 49; ++j) row[j] = r[j] * inv;
    }
    __syncthreads();
    // ---- collapsed V/proj pooling
    if (tid < 49) {
        int i = tid;
        int i7 = i * 37 >> 8;
        int th = wh * 7 + i7, tw = ww * 7 + (i - i7 * 7);
        float s = wsf[OFF_PBS];
        for (int h = 0; h < 2; ++h)
            for (int j = 0; j < 49; ++j)
                s += SM[(h * 49 + i) * 52 + j] * vps[j * 2 + h];
        if (th < 96 && tw < 96) {
            int l = (th * 96 + tw) / 36;
            atomicAdd(&spre[b * 256 + l], s);
        }
    }
}

// ---------------------------------------------------------------- k4: cs = sigmoid(conv2.x1), + sum/min/max
__global__ __launch_bounds__(256) void k4_cs(
    const float* __restrict__ x1, const float* __restrict__ w2,
    float* __restrict__ csb, float* __restrict__ bsum,
    unsigned* __restrict__ bmin, unsigned* __restrict__ bmax) {
    int b = blockIdx.y;
    int n = blockIdx.x * 256 + threadIdx.x;
    float s = 0.f;
    for (int c = 0; c < 128; ++c) s += w2[c] * x1[((size_t)b * 128 + c) * NN + n];
    float csv = 1.f / (1.f + expf(-s));
    csb[(size_t)b * NN + n] = csv;
    float ss = csv, mn = csv, mx = csv;
    for (int o = 32; o > 0; o >>= 1) {
        ss += __shfl_down(ss, o, 64);
        mn = fminf(mn, __shfl_down(mn, o, 64));
        mx = fmaxf(mx, __shfl_down(mx, o, 64));
    }
    if ((threadIdx.x & 63) == 0) {
        atomicAdd(&bsum[b], ss);
        atomicMin(&bmin[b], __float_as_uint(mn));
        atomicMax(&bmax[b], __float_as_uint(mx));
    }
}

// ---------------------------------------------------------------- k5: central moments
__global__ __launch_bounds__(256) void k5_mom(
    const float* __restrict__ csb, const float* __restrict__ bsum,
    float* __restrict__ bm2, float* __restrict__ bm4) {
    int b = blockIdx.y;
    int n = blockIdx.x * 256 + threadIdx.x;
    float mu = bsum[b] * (1.f / 9216.f);
    float d = csb[(size_t)b * NN + n] - mu;
    float d2 = d * d, d4 = d2 * d2;
    for (int o = 32; o > 0; o >>= 1) {
        d2 += __shfl_down(d2, o, 64);
        d4 += __shfl_down(d4, o, 64);
    }
    if ((threadIdx.x & 63) == 0) { atomicAdd(&bm2[b], d2); atomicAdd(&bm4[b], d4); }
}

// ---------------------------------------------------------------- k5b: per-b params
__global__ void k5b_par(const float* __restrict__ bsum, const float* __restrict__ bm2,
                        const float* __restrict__ bm4, const unsigned* __restrict__ bmin,
                        const unsigned* __restrict__ bmax, float* __restrict__ par) {
    int b = threadIdx.x;
    if (b >= 16) return;
    float n = 9216.f;
    float m2 = bm2[b], m4 = bm4[b];
    float var = m2 / (n - 1.f);
    float t1 = n * (n + 1.f) / ((n - 1.f) * (n - 2.f) * (n - 3.f)) * m4 / (var * var);
    float t2 = 3.f * ((n - 1.f) * (n - 1.f)) / ((n - 2.f) * (n - 3.f));
    float kurt = t1 - t2;
    float cmin = __uint_as_float(bmin[b]);
    float cmax = __uint_as_float(bmax[b]);
    float range = cmax - cmin;
    float ql0 = (1.f / 512.f) * range + cmin;
    float ql1 = (3.f / 512.f) * range + cmin;
    float inter = ql1 - ql0;
    par[b * 4 + 0] = fabsf(kurt);
    par[b * 4 + 1] = cmin;
    par[b * 4 + 2] = range;
    par[b * 4 + 3] = 1.f - inter;
}

// ---------------------------------------------------------------- k6: quant output + sta sums
__global__ __launch_bounds__(256) void k6_quant(
    const float* __restrict__ csb, const float* __restrict__ par,
    float* __restrict__ outq, float* __restrict__ staq) {
    int b = blockIdx.y;
    int n0 = blockIdx.x * 64;
    int l = threadIdx.x;
    float absK = par[b * 4 + 0], cmin = par[b * 4 + 1];
    float range = par[b * 4 + 2], thr = par[b * 4 + 3];
    float qlv = ((float)(2 * l + 1) * (1.f / 512.f)) * range + cmin;
    float lsum = 0.f;
    for (int j = 0; j < 64; ++j) {
        float csv = csb[(size_t)b * NN + n0 + j];
        float d = fabsf(qlv - csv);
        float q0 = 1.f - d;
        float qv = absK * expf(-q0);
        float o = (qv > thr) ? qv : 0.f;
        outq[((size_t)(b * NN + n0 + j)) * 256 + l] = o;
        lsum += o;
    }
    atomicAdd(&staq[b * 256 + l], lsum);
}

// ---------------------------------------------------------------- k7: MLP head + BN + ReLU
__global__ __launch_bounds__(256) void k7_head(
    const float* __restrict__ spre, const float* __restrict__ staq,
    const float* __restrict__ f1w, const float* __restrict__ f2w,
    const float* __restrict__ ow, const float* __restrict__ og,
    const float* __restrict__ ob, const float* __restrict__ om,
    const float* __restrict__ ov, const float* __restrict__ gate,
    float* __restrict__ out0) {
    __shared__ float in0[16], in1[16];
    __shared__ float h1[16][64];
    __shared__ __align__(16) float h2[16][132];
    int tid = threadIdx.x;
    int lt = blockIdx.x, b = blockIdx.y;
    if (tid < 16) {
        int l = lt * 16 + tid;
        in0[tid] = gate[0] * (spre[b * 256 + l] * (1.f / 4608.f));
        in1[tid] = staq[b * 256 + l];
    }
    __syncthreads();
    for (int idx = tid; idx < 16 * 64; idx += 256) {
        int j = idx >> 6, o = idx & 63;
        float vv = f1w[o * 2] * in0[j] + f1w[o * 2 + 1] * in1[j];
        h1[j][o] = vv > 0.f ? vv : 0.01f * vv;
    }
    __syncthreads();
    for (int idx = tid; idx < 16 * 128; idx += 256) {
        int j = idx >> 7, o = idx & 127;
        float s = 0.f;
        for (int c = 0; c < 64; ++c) s += f2w[o * 64 + c] * h1[j][c];
        h2[j][o] = fmaxf(s, 0.f);
    }
    __syncthreads();
    {
        int o = tid;
        float acc[16];
#pragma unroll
        for (int j = 0; j < 16; ++j) acc[j] = 0.f;
        for (int c4 = 0; c4 < 128; c4 += 4) {
            float4 w4 = *(const float4*)&ow[(size_t)o * 128 + c4];
#pragma unroll
            for (int j = 0; j < 16; ++j) {
                float4 hh = *(const float4*)&h2[j][c4];
                acc[j] += w4.x * hh.x + w4.y * hh.y + w4.z * hh.z + w4.w * hh.w;
            }
        }
        float sc = og[o] / sqrtf(ov[o] + 1e-5f);
        float bo = ob[o] - om[o] * sc;
        float res[16];
#pragma unroll
        for (int j = 0; j < 16; ++j) { float vv = acc[j] * sc + bo; res[j] = fmaxf(vv, 0.f); }
        float* dst = &out0[((size_t)b * 256 + o) * 256 + lt * 16];
#pragma unroll
        for (int q = 0; q < 4; ++q)
            ((float4*)dst)[q] = make_float4(res[q * 4], res[q * 4 + 1], res[q * 4 + 2], res[q * 4 + 3]);
    }
}

// ----------------------------------------------------------------
extern "C" void kernel_launch(void* const* d_in, const int* in_sizes, int n_in,
                              void* d_out, int out_size, void* d_ws, size_t ws_size,
                              hipStream_t stream) {
    const float* x       = (const float*)d_in[0];
    const float* conv1_w = (const float*)d_in[1];
    const float* bn1_g   = (const float*)d_in[2];
    const float* bn1_b   = (const float*)d_in[3];
    const float* bn1_m   = (const float*)d_in[4];
    const float* bn1_v   = (const float*)d_in[5];
    const float* ln_g    = (const float*)d_in[6];
    const float* ln_b    = (const float*)d_in[7];
    const float* qkv_w   = (const float*)d_in[8];
    const float* qkv_b   = (const float*)d_in[9];
    const float* proj_w  = (const float*)d_in[10];
    const float* proj_b  = (const float*)d_in[11];
    const float* rpe     = (const float*)d_in[12];
    const float* conv2_w = (const float*)d_in[13];
    const float* f1_w    = (const float*)d_in[14];
    const float* f2_w    = (const float*)d_in[15];
    const float* out_w   = (const float*)d_in[16];
    const float* obn_g   = (const float*)d_in[17];
    const float* obn_b   = (const float*)d_in[18];
    const float* obn_m   = (const float*)d_in[19];
    const float* obn_v   = (const float*)d_in[20];
    const float* gate    = (const float*)d_in[21];
    float* wsf  = (float*)d_ws;
    float* out0 = (float*)d_out;
    float* outq = out0 + 1048576;

    // Weight-split scratch in the quant region of d_out (overwritten by k6 later).
    u16* bsh = (u16*)outq;
    u16* bsm = bsh + 294912;
    u16* bsl = bsm + 294912;
    float* bo = (float*)(bsl + 294912);

    hipMemsetAsync(wsf + OFF_SPRE, 0, (size_t)(OFF_BMIN - OFF_SPRE) * 4, stream);
    hipMemsetAsync(wsf + OFF_BMIN, 0xFF, 16 * 4, stream);

    hipLaunchKernelGGL(k0_prep, dim3(1), dim3(256), 0, stream, qkv_w, qkv_b, proj_w, proj_b, wsf);
    hipLaunchKernelGGL(k0c_wsplit, dim3(1152), dim3(256), 0, stream,
                       conv1_w, bn1_g, bn1_b, bn1_m, bn1_v, bsh, bsm, bsl, bo);
    hipLaunchKernelGGL(k1_mfma, dim3(72, 2, 16), dim3(256), 0, stream,
                       x, bsh, bsm, bsl, bo, wsf + OFF_X1);
    hipLaunchKernelGGL(k4_cs, dim3(36, 16), dim3(256), 0, stream,
                       wsf + OFF_X1, conv2_w, wsf + OFF_CS, wsf + OFF_BSUM,
                       (unsigned*)(wsf + OFF_BMIN), (unsigned*)(wsf + OFF_BMAX));
    hipLaunchKernelGGL(k5_mom, dim3(36, 16), dim3(256), 0, stream,
                       wsf + OFF_CS, wsf + OFF_BSUM, wsf + OFF_BM2, wsf + OFF_BM4);
    hipLaunchKernelGGL(k5b_par, dim3(1), dim3(64), 0, stream,
                       wsf + OFF_BSUM, wsf + OFF_BM2, wsf + OFF_BM4,
                       (const unsigned*)(wsf + OFF_BMIN), (const unsigned*)(wsf + OFF_BMAX),
                       wsf + OFF_PAR);
    hipLaunchKernelGGL(k3_attn, dim3(196, 16), dim3(256), 0, stream,
                       wsf + OFF_X1, ln_g, ln_b, qkv_b, rpe, wsf, wsf + OFF_SPRE);
    hipLaunchKernelGGL(k6_quant, dim3(144, 16), dim3(256), 0, stream,
                       wsf + OFF_CS, wsf + OFF_PAR, outq, wsf + OFF_STAQ);
    hipLaunchKernelGGL(k7_head, dim3(16, 16), dim3(256), 0, stream,
                       wsf + OFF_SPRE, wsf + OFF_STAQ, f1_w, f2_w, out_w,
                       obn_g, obn_b, obn_m, obn_v, gate, out0);
}